// Round 8
// baseline (1234.126 us; speedup 1.0000x reference)
//
#include <hip/hip_runtime.h>
#include <math.h>

#define NN 100000
#define NE 1600000
#define CC 128
#define C3 384
#define SCAN_B 256
#define SCAN_NB ((NN + SCAN_B - 1) / SCAN_B)  // 391

typedef __attribute__((ext_vector_type(4))) float f4;
typedef __attribute__((ext_vector_type(8))) short s8;

__device__ __forceinline__ float sigmoidf_(float x) { return 1.0f / (1.0f + __expf(-x)); }
__device__ __forceinline__ float tanhf_(float x) { return 2.0f / (1.0f + __expf(-2.0f * x)) - 1.0f; }

__device__ __forceinline__ short f2bf(float x) {
    unsigned u = __float_as_uint(x);
    unsigned r = (u + 0x7fffu + ((u >> 16) & 1u)) >> 16;
    return (short)r;
}
__device__ __forceinline__ float bf2f(short s) {
    return __uint_as_float(((unsigned)(unsigned short)s) << 16);
}

// ---- edge dtype detection ----
__global__ void k_detect(const int* __restrict__ edges, int* __restrict__ flag) {
    if (threadIdx.x == 0) {
        int allz = 1;
        for (int i = 0; i < 32; i++)
            if (edges[2 * i + 1] != 0) allz = 0;
        *flag = allz;  // 1 => int64 layout
    }
}

__device__ __forceinline__ int edge_val(const void* edges, int f, long long idx) {
    return f ? (int)((const long long*)edges)[idx] : ((const int*)edges)[idx];
}

__global__ void k_count(const void* __restrict__ edges, const int* __restrict__ flag,
                        int* __restrict__ counts) {
    int e = blockIdx.x * blockDim.x + threadIdx.x;
    if (e < NE) {
        int f = *flag;
        int d = edge_val(edges, f, (long long)NE + e);
        atomicAdd(&counts[d], 1);
    }
}

// ---- multi-block scan ----
__global__ void k_scan1(const int* __restrict__ counts, int* __restrict__ bsum) {
    __shared__ int red[4];
    int t = threadIdx.x;
    int i = blockIdx.x * SCAN_B + t;
    int v = (i < NN) ? counts[i] : 0;
#pragma unroll
    for (int off = 32; off; off >>= 1) v += __shfl_down(v, off);
    if ((t & 63) == 0) red[t >> 6] = v;
    __syncthreads();
    if (t == 0) bsum[blockIdx.x] = red[0] + red[1] + red[2] + red[3];
}

__global__ void k_scan2(const int* __restrict__ bsum, int* __restrict__ boff) {
    __shared__ int lds[512];
    int t = threadIdx.x;
    int v = (t < SCAN_NB) ? bsum[t] : 0;
    lds[t] = v;
    __syncthreads();
    for (int off = 1; off < 512; off <<= 1) {
        int u = (t >= off) ? lds[t - off] : 0;
        __syncthreads();
        lds[t] += u;
        __syncthreads();
    }
    if (t < SCAN_NB) boff[t] = lds[t] - v;  // exclusive
}

__global__ void k_scan3(const int* __restrict__ counts, const int* __restrict__ boff,
                        int* __restrict__ rowptr, float* __restrict__ inv_denom) {
    __shared__ int lds[SCAN_B];
    int t = threadIdx.x;
    int i = blockIdx.x * SCAN_B + t;
    int v = (i < NN) ? counts[i] : 0;
    lds[t] = v;
    __syncthreads();
    for (int off = 1; off < SCAN_B; off <<= 1) {
        int u = (t >= off) ? lds[t - off] : 0;
        __syncthreads();
        lds[t] += u;
        __syncthreads();
    }
    if (i < NN) {
        rowptr[i] = boff[blockIdx.x] + lds[t] - v;
        inv_denom[i] = 1.0f / (float)((v > 1) ? v : 1);
    }
    if (i == 0) rowptr[NN] = NE;
}

__global__ void k_bucket(const void* __restrict__ edges, const int* __restrict__ flag,
                         const int* __restrict__ rowptr, int* __restrict__ cursor,
                         int* __restrict__ csr_src) {
    int e = blockIdx.x * blockDim.x + threadIdx.x;
    if (e < NE) {
        int f = *flag;
        int s = edge_val(edges, f, e);
        int d = edge_val(edges, f, (long long)NE + e);
        int pos = atomicAdd(&cursor[d], 1);
        csr_src[rowptr[d] + pos] = s;
    }
}

// ---- weight prep (validated R2) ----
__global__ void k_prep(const float* __restrict__ weight, const float* __restrict__ w_ih,
                       const float* __restrict__ w_hh, const float* __restrict__ b_ih,
                       const float* __restrict__ b_hh,
                       short* __restrict__ B1hi, short* __restrict__ B1lo,
                       short* __restrict__ B2hi, short* __restrict__ B2lo,
                       float* __restrict__ bvec) {
    const int P1 = 3 * C3 * CC;
    int gid = blockIdx.x * blockDim.x + threadIdx.x;
    if (gid < P1) {
        int i = gid / (C3 * CC);
        int rem = gid % (C3 * CC);
        int j = rem / CC;
        int k = rem % CC;
        const float* Wr = weight + i * CC * CC + k * CC;
        const float* ir = w_ih + j * CC;
        float v = 0.f;
#pragma unroll 4
        for (int c = 0; c < CC; c++) v += Wr[c] * ir[c];
        short hi = f2bf(v);
        short lo = f2bf(v - bf2f(hi));
        if (j < 256) {
            int idx = i * 65536 + j * 256 + k;
            B1hi[idx] = hi; B1lo[idx] = lo;
        } else {
            int idx = i * 32768 + (j - 256) * 128 + k;
            B2hi[idx] = hi; B2lo[idx] = lo;
        }
    } else if (gid < 2 * P1) {
        int g = gid - P1;
        int i = g / (C3 * CC);
        int rem = g % (C3 * CC);
        int j = rem / CC;
        int k = rem % CC;
        float v = w_hh[j * CC + k];
        short hi = f2bf(v);
        short lo = f2bf(v - bf2f(hi));
        if (j < 256) {
            int idx = i * 65536 + j * 256 + 128 + k;
            B1hi[idx] = hi; B1lo[idx] = lo;
        } else {
            int idx = i * 32768 + (j - 256 + 128) * 128 + k;
            B2hi[idx] = hi; B2lo[idx] = lo;
        }
    } else if (gid < 2 * P1 + 512) {
        int j = gid - 2 * P1;
        float v;
        if (j < 256) v = b_ih[j] + b_hh[j];
        else if (j < 384) v = b_ih[j];
        else v = b_hh[j - 128];
        bvec[j] = v;
    }
}

// ---- x -> split-bf16 dense hhi/hlo ----
__global__ void k_cvt(const float* __restrict__ x, unsigned short* __restrict__ hhi,
                      unsigned short* __restrict__ hlo) {
    long long g = ((long long)blockIdx.x * 256 + threadIdx.x) * 8;
    float4 v0 = *(const float4*)(x + g);
    float4 v1 = *(const float4*)(x + g + 4);
    float f[8] = {v0.x, v0.y, v0.z, v0.w, v1.x, v1.y, v1.z, v1.w};
    s8 oh, ol;
#pragma unroll
    for (int q = 0; q < 8; q++) {
        short hi = f2bf(f[q]);
        oh[q] = hi;
        ol[q] = f2bf(f[q] - bf2f(hi));
    }
    *(s8*)(hhi + g) = oh;
    *(s8*)(hlo + g) = ol;
}

// ---- aggregation: gather bf16 hhi (256 B dense rows); write split-bf16 a_hat dense ----
__global__ void k_agg(const unsigned short* __restrict__ hhi,
                      unsigned short* __restrict__ aghi, unsigned short* __restrict__ aglo,
                      const int* __restrict__ rowptr, const int* __restrict__ csr_src,
                      const float* __restrict__ inv_denom) {
    int wid = (blockIdx.x * blockDim.x + threadIdx.x) >> 6;
    int lane = threadIdx.x & 63;
    if (wid >= NN) return;
    int lo = rowptr[wid], hi = rowptr[wid + 1];
    int half = lane >> 5;
    int l32 = lane & 31;
    float a0 = 0.f, a1 = 0.f, a2 = 0.f, a3 = 0.f;
    for (int e = lo + half; e < hi; e += 2) {
        int s = csr_src[e];
        ushort4 v = ((const ushort4*)(hhi + (long long)s * CC))[l32];
        a0 += bf2f((short)v.x);
        a1 += bf2f((short)v.y);
        a2 += bf2f((short)v.z);
        a3 += bf2f((short)v.w);
    }
    a0 += __shfl_down(a0, 32);
    a1 += __shfl_down(a1, 32);
    a2 += __shfl_down(a2, 32);
    a3 += __shfl_down(a3, 32);
    if (half == 0) {
        float inv = inv_denom[wid];
        float s[4] = {a0 * inv, a1 * inv, a2 * inv, a3 * inv};
        ushort4 vh, vl;
        short h0 = f2bf(s[0]); vh.x = (unsigned short)h0; vl.x = (unsigned short)f2bf(s[0] - bf2f(h0));
        short h1 = f2bf(s[1]); vh.y = (unsigned short)h1; vl.y = (unsigned short)f2bf(s[1] - bf2f(h1));
        short h2 = f2bf(s[2]); vh.z = (unsigned short)h2; vl.z = (unsigned short)f2bf(s[2] - bf2f(h2));
        short h3 = f2bf(s[3]); vh.w = (unsigned short)h3; vl.w = (unsigned short)f2bf(s[3] - bf2f(h3));
        ((ushort4*)(aghi + (long long)wid * CC))[l32] = vh;
        ((ushort4*)(aglo + (long long)wid * CC))[l32] = vl;
    }
}

// ---- fused split-bf16 MFMA GEMM + GRU, 32 nodes/block, 4 dense bf16 arrays ----
// A = [a_hat | h], hi/lo pre-split in aghi/aglo (cols 0-127) and hhi/hlo (128-255),
// all dense 256 B/row (R6's proven write pattern: WRITE == logical). Staging is
// branch-free s8 copies (half selector is a uniform unrolled loop).
// LDS fragment order (shorts): off = (c4>>2)*1024 + (rr>>4)*512 + (rr&15)*32 + (c4&3)*8.
__global__ __launch_bounds__(256, 4) void k_gru_mfma(
    const unsigned short* __restrict__ aghi, const unsigned short* __restrict__ aglo,
    unsigned short* __restrict__ hhi, unsigned short* __restrict__ hlo,
    const short* __restrict__ B1hi, const short* __restrict__ B1lo,
    const short* __restrict__ B2hi, const short* __restrict__ B2lo,
    const float* __restrict__ bvec) {
    __shared__ short Ahi[8192];
    __shared__ short Alo[8192];
    int t = threadIdx.x;
    long long nb = (long long)blockIdx.x * 32;

#pragma unroll
    for (int half = 0; half < 2; half++) {
        const unsigned short* sh = half ? hhi : aghi;
        const unsigned short* sl = half ? hlo : aglo;
#pragma unroll
        for (int i = 0; i < 2; i++) {
            int ci = t + 256 * i;       // 0..511 = 32 rows x 16 chunks
            int rr = ci >> 4;
            int c = ci & 15;
            int c4 = half * 16 + c;
            int off = (c4 >> 2) * 1024 + (rr >> 4) * 512 + (rr & 15) * 32 + (c4 & 3) * 8;
            long long gsrc = (nb + rr) * CC + c * 8;
            *(s8*)&Ahi[off] = *(const s8*)(sh + gsrc);
            *(s8*)&Alo[off] = *(const s8*)(sl + gsrc);
        }
    }
    __syncthreads();

    int wv = t >> 6;
    int L = t & 63;
    int lm = L & 15;
    int lq = L >> 4;
    int g0 = 2 * wv;

    f4 aR[2][2], aZ[2][2], aN[2][2], aH[2][2];
#pragma unroll
    for (int gp = 0; gp < 2; gp++) {
        int j = (g0 + gp) * 16 + lm;
        float bR = bvec[j], bZ = bvec[128 + j], bN = bvec[256 + j], bH = bvec[384 + j];
#pragma unroll
        for (int ch = 0; ch < 2; ch++) {
            aR[gp][ch] = (f4){bR, bR, bR, bR};
            aZ[gp][ch] = (f4){bZ, bZ, bZ, bZ};
            aN[gp][ch] = (f4){bN, bN, bN, bN};
            aH[gp][ch] = (f4){bH, bH, bH, bH};
        }
    }

#pragma unroll
    for (int ks = 0; ks < 8; ks++) {
        s8 bRh[2], bRl[2], bZh[2], bZl[2], bGh[2], bGl[2];
#pragma unroll
        for (int gp = 0; gp < 2; gp++) {
            int rowR = (g0 + gp) * 16 + lm;
            int o1 = ks * 32 + lq * 8;
            bRh[gp] = *(const s8*)(B1hi + rowR * 256 + o1);
            bRl[gp] = *(const s8*)(B1lo + rowR * 256 + o1);
            bZh[gp] = *(const s8*)(B1hi + (128 + rowR) * 256 + o1);
            bZl[gp] = *(const s8*)(B1lo + (128 + rowR) * 256 + o1);
            int rowG = (ks < 4) ? rowR : (128 + rowR);
            int o2 = (ks & 3) * 32 + lq * 8;
            bGh[gp] = *(const s8*)(B2hi + rowG * 128 + o2);
            bGl[gp] = *(const s8*)(B2lo + rowG * 128 + o2);
        }
#pragma unroll
        for (int ch = 0; ch < 2; ch++) {
            int aoff = ks * 1024 + ch * 512 + lm * 32 + lq * 8;
            s8 ah = *(const s8*)&Ahi[aoff];
            s8 al = *(const s8*)&Alo[aoff];
#pragma unroll
            for (int gp = 0; gp < 2; gp++) {
                aR[gp][ch] = __builtin_amdgcn_mfma_f32_16x16x32_bf16(ah, bRh[gp], aR[gp][ch], 0, 0, 0);
                aR[gp][ch] = __builtin_amdgcn_mfma_f32_16x16x32_bf16(al, bRh[gp], aR[gp][ch], 0, 0, 0);
                aR[gp][ch] = __builtin_amdgcn_mfma_f32_16x16x32_bf16(ah, bRl[gp], aR[gp][ch], 0, 0, 0);
                aZ[gp][ch] = __builtin_amdgcn_mfma_f32_16x16x32_bf16(ah, bZh[gp], aZ[gp][ch], 0, 0, 0);
                aZ[gp][ch] = __builtin_amdgcn_mfma_f32_16x16x32_bf16(al, bZh[gp], aZ[gp][ch], 0, 0, 0);
                aZ[gp][ch] = __builtin_amdgcn_mfma_f32_16x16x32_bf16(ah, bZl[gp], aZ[gp][ch], 0, 0, 0);
                if (ks < 4) {
                    aN[gp][ch] = __builtin_amdgcn_mfma_f32_16x16x32_bf16(ah, bGh[gp], aN[gp][ch], 0, 0, 0);
                    aN[gp][ch] = __builtin_amdgcn_mfma_f32_16x16x32_bf16(al, bGh[gp], aN[gp][ch], 0, 0, 0);
                    aN[gp][ch] = __builtin_amdgcn_mfma_f32_16x16x32_bf16(ah, bGl[gp], aN[gp][ch], 0, 0, 0);
                } else {
                    aH[gp][ch] = __builtin_amdgcn_mfma_f32_16x16x32_bf16(ah, bGh[gp], aH[gp][ch], 0, 0, 0);
                    aH[gp][ch] = __builtin_amdgcn_mfma_f32_16x16x32_bf16(al, bGh[gp], aH[gp][ch], 0, 0, 0);
                    aH[gp][ch] = __builtin_amdgcn_mfma_f32_16x16x32_bf16(ah, bGl[gp], aH[gp][ch], 0, 0, 0);
                }
            }
        }
    }

    // register-only GRU epilogue; h written back in place (dense split-bf16)
#pragma unroll
    for (int gp = 0; gp < 2; gp++) {
        int j = (g0 + gp) * 16 + lm;
        int c4 = 16 + (j >> 3);
        int obase = (c4 >> 2) * 1024 + (c4 & 3) * 8 + (j & 7);
#pragma unroll
        for (int ch = 0; ch < 2; ch++) {
#pragma unroll
            for (int r = 0; r < 4; r++) {
                int node = ch * 16 + lq * 4 + r;
                int off = obase + ch * 512 + (node & 15) * 32;
                float hp = bf2f(Ahi[off]) + bf2f(Alo[off]);
                float sr = aR[gp][ch][r];
                float sz = aZ[gp][ch][r];
                float in_ = aN[gp][ch][r];
                float hn = aH[gp][ch][r];
                float rg = sigmoidf_(sr);
                float zg = sigmoidf_(sz);
                float nv = tanhf_(in_ + rg * hn);
                float val = (1.f - zg) * nv + zg * hp;
                long long gd = (nb + node) * CC + j;
                short vh = f2bf(val);
                hhi[gd] = (unsigned short)vh;
                hlo[gd] = (unsigned short)f2bf(val - bf2f(vh));
            }
        }
    }
}

// ---- out[n] = tanh(mean_c (hi+lo)) ----
__global__ void k_out(const unsigned short* __restrict__ hhi,
                      const unsigned short* __restrict__ hlo, float* __restrict__ out) {
    int wid = (blockIdx.x * blockDim.x + threadIdx.x) >> 6;
    int lane = threadIdx.x & 63;
    if (wid >= NN) return;
    ushort2 vh = ((const ushort2*)(hhi + (long long)wid * CC))[lane];
    ushort2 vl = ((const ushort2*)(hlo + (long long)wid * CC))[lane];
    float s = bf2f((short)vh.x) + bf2f((short)vl.x) + bf2f((short)vh.y) + bf2f((short)vl.y);
    for (int off = 32; off; off >>= 1) s += __shfl_down(s, off);
    if (lane == 0) out[wid] = tanhf_(s * (1.0f / 128.0f));
}

extern "C" void kernel_launch(void* const* d_in, const int* in_sizes, int n_in,
                              void* d_out, int out_size, void* d_ws, size_t ws_size,
                              hipStream_t stream) {
    const float* x = (const float*)d_in[0];
    const void* edges = d_in[1];
    const float* weight = (const float*)d_in[2];
    const float* w_ih = (const float*)d_in[3];
    const float* w_hh = (const float*)d_in[4];
    const float* b_ih = (const float*)d_in[5];
    const float* b_hh = (const float*)d_in[6];
    float* out = (float*)d_out;

    char* ws = (char*)d_ws;
    size_t off = 0;
    auto alloc = [&](size_t bytes) -> char* {
        char* p = ws + off;
        off += (bytes + 255) & ~(size_t)255;
        return p;
    };
    // total ws ~112 MB (proven-safe watermark from R4: 162.8 MB)
    int* flag = (int*)alloc(4);
    int* counts = (int*)alloc((size_t)NN * 4);
    int* cursor = (int*)alloc((size_t)NN * 4);
    int* rowptr = (int*)alloc((size_t)(NN + 1) * 4);
    int* csr_src = (int*)alloc((size_t)NE * 4);
    float* inv_den = (float*)alloc((size_t)NN * 4);
    int* bsum = (int*)alloc((size_t)SCAN_NB * 4);
    int* boff = (int*)alloc((size_t)SCAN_NB * 4);
    short* B1hi = (short*)alloc((size_t)3 * 65536 * 2);
    short* B1lo = (short*)alloc((size_t)3 * 65536 * 2);
    short* B2hi = (short*)alloc((size_t)3 * 32768 * 2);
    short* B2lo = (short*)alloc((size_t)3 * 32768 * 2);
    float* bvec = (float*)alloc(512 * 4);
    unsigned short* aghi = (unsigned short*)alloc((size_t)NN * CC * 2);
    unsigned short* aglo = (unsigned short*)alloc((size_t)NN * CC * 2);
    unsigned short* hhi = (unsigned short*)alloc((size_t)NN * CC * 2);
    unsigned short* hlo = (unsigned short*)alloc((size_t)NN * CC * 2);

    hipMemsetAsync(counts, 0, (size_t)NN * 4, stream);
    hipMemsetAsync(cursor, 0, (size_t)NN * 4, stream);

    k_detect<<<1, 64, 0, stream>>>((const int*)edges, flag);
    k_count<<<(NE + 255) / 256, 256, 0, stream>>>(edges, flag, counts);
    k_scan1<<<SCAN_NB, SCAN_B, 0, stream>>>(counts, bsum);
    k_scan2<<<1, 512, 0, stream>>>(bsum, boff);
    k_scan3<<<SCAN_NB, SCAN_B, 0, stream>>>(counts, boff, rowptr, inv_den);
    k_bucket<<<(NE + 255) / 256, 256, 0, stream>>>(edges, flag, rowptr, cursor, csr_src);
    int prep_threads = 2 * 3 * C3 * CC + 512;
    k_prep<<<(prep_threads + 255) / 256, 256, 0, stream>>>(weight, w_ih, w_hh, b_ih, b_hh,
                                                           B1hi, B1lo, B2hi, B2lo, bvec);
    k_cvt<<<(NN * CC) / 2048, 256, 0, stream>>>(x, hhi, hlo);

    const int gru_blocks = NN / 32;  // 3125 exact
    for (int i = 0; i < 3; i++) {
        k_agg<<<25000, 256, 0, stream>>>(hhi, aghi, aglo, rowptr, csr_src, inv_den);
        k_gru_mfma<<<gru_blocks, 256, 0, stream>>>(aghi, aglo, hhi, hlo,
                                                   B1hi + (size_t)i * 65536, B1lo + (size_t)i * 65536,
                                                   B2hi + (size_t)i * 32768, B2lo + (size_t)i * 32768,
                                                   bvec);
    }
    k_out<<<25000, 256, 0, stream>>>(hhi, hlo, out);
}

// Round 9
// 897.338 us; speedup vs baseline: 1.3753x; 1.3753x over previous
//
#include <hip/hip_runtime.h>
#include <math.h>

#define NN 100000
#define NE 1600000
#define CC 128
#define C3 384
#define SCAN_B 256
#define SCAN_NB ((NN + SCAN_B - 1) / SCAN_B)  // 391

typedef __attribute__((ext_vector_type(4))) float f4;
typedef __attribute__((ext_vector_type(8))) short s8;

__device__ __forceinline__ float sigmoidf_(float x) { return 1.0f / (1.0f + __expf(-x)); }
__device__ __forceinline__ float tanhf_(float x) { return 2.0f / (1.0f + __expf(-2.0f * x)) - 1.0f; }

__device__ __forceinline__ short f2bf(float x) {
    unsigned u = __float_as_uint(x);
    unsigned r = (u + 0x7fffu + ((u >> 16) & 1u)) >> 16;
    return (short)r;
}
__device__ __forceinline__ float bf2f(short s) {
    return __uint_as_float(((unsigned)(unsigned short)s) << 16);
}

// ---- edge dtype detection ----
__global__ void k_detect(const int* __restrict__ edges, int* __restrict__ flag) {
    if (threadIdx.x == 0) {
        int allz = 1;
        for (int i = 0; i < 32; i++)
            if (edges[2 * i + 1] != 0) allz = 0;
        *flag = allz;  // 1 => int64 layout
    }
}

__device__ __forceinline__ int edge_val(const void* edges, int f, long long idx) {
    return f ? (int)((const long long*)edges)[idx] : ((const int*)edges)[idx];
}

__global__ void k_count(const void* __restrict__ edges, const int* __restrict__ flag,
                        int* __restrict__ counts) {
    int e = blockIdx.x * blockDim.x + threadIdx.x;
    if (e < NE) {
        int f = *flag;
        int d = edge_val(edges, f, (long long)NE + e);
        atomicAdd(&counts[d], 1);
    }
}

// ---- multi-block scan ----
__global__ void k_scan1(const int* __restrict__ counts, int* __restrict__ bsum) {
    __shared__ int red[4];
    int t = threadIdx.x;
    int i = blockIdx.x * SCAN_B + t;
    int v = (i < NN) ? counts[i] : 0;
#pragma unroll
    for (int off = 32; off; off >>= 1) v += __shfl_down(v, off);
    if ((t & 63) == 0) red[t >> 6] = v;
    __syncthreads();
    if (t == 0) bsum[blockIdx.x] = red[0] + red[1] + red[2] + red[3];
}

__global__ void k_scan2(const int* __restrict__ bsum, int* __restrict__ boff) {
    __shared__ int lds[512];
    int t = threadIdx.x;
    int v = (t < SCAN_NB) ? bsum[t] : 0;
    lds[t] = v;
    __syncthreads();
    for (int off = 1; off < 512; off <<= 1) {
        int u = (t >= off) ? lds[t - off] : 0;
        __syncthreads();
        lds[t] += u;
        __syncthreads();
    }
    if (t < SCAN_NB) boff[t] = lds[t] - v;  // exclusive
}

__global__ void k_scan3(const int* __restrict__ counts, const int* __restrict__ boff,
                        int* __restrict__ rowptr, float* __restrict__ inv_denom) {
    __shared__ int lds[SCAN_B];
    int t = threadIdx.x;
    int i = blockIdx.x * SCAN_B + t;
    int v = (i < NN) ? counts[i] : 0;
    lds[t] = v;
    __syncthreads();
    for (int off = 1; off < SCAN_B; off <<= 1) {
        int u = (t >= off) ? lds[t - off] : 0;
        __syncthreads();
        lds[t] += u;
        __syncthreads();
    }
    if (i < NN) {
        rowptr[i] = boff[blockIdx.x] + lds[t] - v;
        inv_denom[i] = 1.0f / (float)((v > 1) ? v : 1);
    }
    if (i == 0) rowptr[NN] = NE;
}

__global__ void k_bucket(const void* __restrict__ edges, const int* __restrict__ flag,
                         const int* __restrict__ rowptr, int* __restrict__ cursor,
                         int* __restrict__ csr_src) {
    int e = blockIdx.x * blockDim.x + threadIdx.x;
    if (e < NE) {
        int f = *flag;
        int s = edge_val(edges, f, e);
        int d = edge_val(edges, f, (long long)NE + e);
        int pos = atomicAdd(&cursor[d], 1);
        csr_src[rowptr[d] + pos] = s;
    }
}

// ---- weight prep (validated R2) ----
__global__ void k_prep(const float* __restrict__ weight, const float* __restrict__ w_ih,
                       const float* __restrict__ w_hh, const float* __restrict__ b_ih,
                       const float* __restrict__ b_hh,
                       short* __restrict__ B1hi, short* __restrict__ B1lo,
                       short* __restrict__ B2hi, short* __restrict__ B2lo,
                       float* __restrict__ bvec) {
    const int P1 = 3 * C3 * CC;
    int gid = blockIdx.x * blockDim.x + threadIdx.x;
    if (gid < P1) {
        int i = gid / (C3 * CC);
        int rem = gid % (C3 * CC);
        int j = rem / CC;
        int k = rem % CC;
        const float* Wr = weight + i * CC * CC + k * CC;
        const float* ir = w_ih + j * CC;
        float v = 0.f;
#pragma unroll 4
        for (int c = 0; c < CC; c++) v += Wr[c] * ir[c];
        short hi = f2bf(v);
        short lo = f2bf(v - bf2f(hi));
        if (j < 256) {
            int idx = i * 65536 + j * 256 + k;
            B1hi[idx] = hi; B1lo[idx] = lo;
        } else {
            int idx = i * 32768 + (j - 256) * 128 + k;
            B2hi[idx] = hi; B2lo[idx] = lo;
        }
    } else if (gid < 2 * P1) {
        int g = gid - P1;
        int i = g / (C3 * CC);
        int rem = g % (C3 * CC);
        int j = rem / CC;
        int k = rem % CC;
        float v = w_hh[j * CC + k];
        short hi = f2bf(v);
        short lo = f2bf(v - bf2f(hi));
        if (j < 256) {
            int idx = i * 65536 + j * 256 + 128 + k;
            B1hi[idx] = hi; B1lo[idx] = lo;
        } else {
            int idx = i * 32768 + (j - 256 + 128) * 128 + k;
            B2hi[idx] = hi; B2lo[idx] = lo;
        }
    } else if (gid < 2 * P1 + 512) {
        int j = gid - 2 * P1;
        float v;
        if (j < 256) v = b_ih[j] + b_hh[j];
        else if (j < 384) v = b_ih[j];
        else v = b_hh[j - 128];
        bvec[j] = v;
    }
}

// ---- x -> split-bf16 dense hhi/hlo ----
__global__ void k_cvt(const float* __restrict__ x, unsigned short* __restrict__ hhi,
                      unsigned short* __restrict__ hlo) {
    long long g = ((long long)blockIdx.x * 256 + threadIdx.x) * 8;
    float4 v0 = *(const float4*)(x + g);
    float4 v1 = *(const float4*)(x + g + 4);
    float f[8] = {v0.x, v0.y, v0.z, v0.w, v1.x, v1.y, v1.z, v1.w};
    s8 oh, ol;
#pragma unroll
    for (int q = 0; q < 8; q++) {
        short hi = f2bf(f[q]);
        oh[q] = hi;
        ol[q] = f2bf(f[q] - bf2f(hi));
    }
    *(s8*)(hhi + g) = oh;
    *(s8*)(hlo + g) = ol;
}

// ---- aggregation: gather bf16 hhi (256 B dense rows); write split-bf16 a_hat dense ----
__global__ void k_agg(const unsigned short* __restrict__ hhi,
                      unsigned short* __restrict__ aghi, unsigned short* __restrict__ aglo,
                      const int* __restrict__ rowptr, const int* __restrict__ csr_src,
                      const float* __restrict__ inv_denom) {
    int wid = (blockIdx.x * blockDim.x + threadIdx.x) >> 6;
    int lane = threadIdx.x & 63;
    if (wid >= NN) return;
    int lo = rowptr[wid], hi = rowptr[wid + 1];
    int half = lane >> 5;
    int l32 = lane & 31;
    float a0 = 0.f, a1 = 0.f, a2 = 0.f, a3 = 0.f;
    for (int e = lo + half; e < hi; e += 2) {
        int s = csr_src[e];
        ushort4 v = ((const ushort4*)(hhi + (long long)s * CC))[l32];
        a0 += bf2f((short)v.x);
        a1 += bf2f((short)v.y);
        a2 += bf2f((short)v.z);
        a3 += bf2f((short)v.w);
    }
    a0 += __shfl_down(a0, 32);
    a1 += __shfl_down(a1, 32);
    a2 += __shfl_down(a2, 32);
    a3 += __shfl_down(a3, 32);
    if (half == 0) {
        float inv = inv_denom[wid];
        float s[4] = {a0 * inv, a1 * inv, a2 * inv, a3 * inv};
        ushort4 vh, vl;
        short h0 = f2bf(s[0]); vh.x = (unsigned short)h0; vl.x = (unsigned short)f2bf(s[0] - bf2f(h0));
        short h1 = f2bf(s[1]); vh.y = (unsigned short)h1; vl.y = (unsigned short)f2bf(s[1] - bf2f(h1));
        short h2 = f2bf(s[2]); vh.z = (unsigned short)h2; vl.z = (unsigned short)f2bf(s[2] - bf2f(h2));
        short h3 = f2bf(s[3]); vh.w = (unsigned short)h3; vl.w = (unsigned short)f2bf(s[3] - bf2f(h3));
        ((ushort4*)(aghi + (long long)wid * CC))[l32] = vh;
        ((ushort4*)(aglo + (long long)wid * CC))[l32] = vl;
    }
}

// ---- fused split-bf16 MFMA GEMM + GRU, v5 ----
// 64 nodes/block (K6's proven ~logical-traffic shape), 512 threads = 8 waves,
// one gate-feature block g per wave; 2 blocks/CU -> 4 waves/SIMD (2x K6 hiding).
// Staging branch-free s8 copies from pre-split dense arrays. LDS 32 KB x2.
// LDS frag order (shorts): off = (c4>>2)*2048 + (rr>>4)*512 + (rr&15)*32 + (c4&3)*8.
__global__ __launch_bounds__(512, 4) void k_gru_mfma(
    const unsigned short* __restrict__ aghi, const unsigned short* __restrict__ aglo,
    unsigned short* __restrict__ hhi, unsigned short* __restrict__ hlo,
    const short* __restrict__ B1hi, const short* __restrict__ B1lo,
    const short* __restrict__ B2hi, const short* __restrict__ B2lo,
    const float* __restrict__ bvec) {
    __shared__ short Ahi[16384];
    __shared__ short Alo[16384];
    int t = threadIdx.x;
    long long nb = (long long)blockIdx.x * 64;

    // staging: 64 rows x 16 chunks per half = 1024 chunk-copies/half; 2 iters/thread
#pragma unroll
    for (int half = 0; half < 2; half++) {
        const unsigned short* sh = half ? hhi : aghi;
        const unsigned short* sl = half ? hlo : aglo;
#pragma unroll
        for (int i = 0; i < 2; i++) {
            int ci = t + 512 * i;        // 0..1023
            int rr = ci >> 4;            // 0..63
            int c = ci & 15;             // 0..15
            int c4 = half * 16 + c;
            long long row = nb + rr;
            if (row >= NN) row = NN - 1;
            int off = (c4 >> 2) * 2048 + (rr >> 4) * 512 + (rr & 15) * 32 + (c4 & 3) * 8;
            long long gsrc = row * CC + c * 8;
            *(s8*)&Ahi[off] = *(const s8*)(sh + gsrc);
            *(s8*)&Alo[off] = *(const s8*)(sl + gsrc);
        }
    }
    __syncthreads();

    int wv = t >> 6;   // 0..7 = gate-feature block
    int L = t & 63;
    int lm = L & 15;
    int lq = L >> 4;
    int j = wv * 16 + lm;

    f4 aR[4], aZ[4], aN[4], aH[4];
    {
        float bR = bvec[j], bZ = bvec[128 + j], bN = bvec[256 + j], bH = bvec[384 + j];
#pragma unroll
        for (int ch = 0; ch < 4; ch++) {
            aR[ch] = (f4){bR, bR, bR, bR};
            aZ[ch] = (f4){bZ, bZ, bZ, bZ};
            aN[ch] = (f4){bN, bN, bN, bN};
            aH[ch] = (f4){bH, bH, bH, bH};
        }
    }

#pragma unroll
    for (int ks = 0; ks < 8; ks++) {
        int o1 = ks * 32 + lq * 8;
        s8 bRh = *(const s8*)(B1hi + j * 256 + o1);
        s8 bRl = *(const s8*)(B1lo + j * 256 + o1);
        s8 bZh = *(const s8*)(B1hi + (128 + j) * 256 + o1);
        s8 bZl = *(const s8*)(B1lo + (128 + j) * 256 + o1);
        int rowG = (ks < 4) ? j : (128 + j);
        int o2 = (ks & 3) * 32 + lq * 8;
        s8 bGh = *(const s8*)(B2hi + rowG * 128 + o2);
        s8 bGl = *(const s8*)(B2lo + rowG * 128 + o2);
#pragma unroll
        for (int ch = 0; ch < 4; ch++) {
            int aoff = ks * 2048 + ch * 512 + lm * 32 + lq * 8;
            s8 ah = *(const s8*)&Ahi[aoff];
            s8 al = *(const s8*)&Alo[aoff];
            aR[ch] = __builtin_amdgcn_mfma_f32_16x16x32_bf16(ah, bRh, aR[ch], 0, 0, 0);
            aR[ch] = __builtin_amdgcn_mfma_f32_16x16x32_bf16(al, bRh, aR[ch], 0, 0, 0);
            aR[ch] = __builtin_amdgcn_mfma_f32_16x16x32_bf16(ah, bRl, aR[ch], 0, 0, 0);
            aZ[ch] = __builtin_amdgcn_mfma_f32_16x16x32_bf16(ah, bZh, aZ[ch], 0, 0, 0);
            aZ[ch] = __builtin_amdgcn_mfma_f32_16x16x32_bf16(al, bZh, aZ[ch], 0, 0, 0);
            aZ[ch] = __builtin_amdgcn_mfma_f32_16x16x32_bf16(ah, bZl, aZ[ch], 0, 0, 0);
            if (ks < 4) {
                aN[ch] = __builtin_amdgcn_mfma_f32_16x16x32_bf16(ah, bGh, aN[ch], 0, 0, 0);
                aN[ch] = __builtin_amdgcn_mfma_f32_16x16x32_bf16(al, bGh, aN[ch], 0, 0, 0);
                aN[ch] = __builtin_amdgcn_mfma_f32_16x16x32_bf16(ah, bGl, aN[ch], 0, 0, 0);
            } else {
                aH[ch] = __builtin_amdgcn_mfma_f32_16x16x32_bf16(ah, bGh, aH[ch], 0, 0, 0);
                aH[ch] = __builtin_amdgcn_mfma_f32_16x16x32_bf16(al, bGh, aH[ch], 0, 0, 0);
                aH[ch] = __builtin_amdgcn_mfma_f32_16x16x32_bf16(ah, bGl, aH[ch], 0, 0, 0);
            }
        }
    }

    // register-only GRU epilogue; h written back in place (dense split-bf16)
    {
        int c4 = 16 + (j >> 3);
        int obase = (c4 >> 2) * 2048 + (c4 & 3) * 8 + (j & 7);
#pragma unroll
        for (int ch = 0; ch < 4; ch++) {
#pragma unroll
            for (int r = 0; r < 4; r++) {
                int node = ch * 16 + lq * 4 + r;
                int off = obase + ch * 512 + (node & 15) * 32;
                float hp = bf2f(Ahi[off]) + bf2f(Alo[off]);
                float sr = aR[ch][r];
                float sz = aZ[ch][r];
                float in_ = aN[ch][r];
                float hn = aH[ch][r];
                float rg = sigmoidf_(sr);
                float zg = sigmoidf_(sz);
                float nv = tanhf_(in_ + rg * hn);
                float val = (1.f - zg) * nv + zg * hp;
                long long gnode = nb + node;
                if (gnode < NN) {
                    long long gd = gnode * CC + j;
                    short vh = f2bf(val);
                    hhi[gd] = (unsigned short)vh;
                    hlo[gd] = (unsigned short)f2bf(val - bf2f(vh));
                }
            }
        }
    }
}

// ---- out[n] = tanh(mean_c (hi+lo)) ----
__global__ void k_out(const unsigned short* __restrict__ hhi,
                      const unsigned short* __restrict__ hlo, float* __restrict__ out) {
    int wid = (blockIdx.x * blockDim.x + threadIdx.x) >> 6;
    int lane = threadIdx.x & 63;
    if (wid >= NN) return;
    ushort2 vh = ((const ushort2*)(hhi + (long long)wid * CC))[lane];
    ushort2 vl = ((const ushort2*)(hlo + (long long)wid * CC))[lane];
    float s = bf2f((short)vh.x) + bf2f((short)vl.x) + bf2f((short)vh.y) + bf2f((short)vl.y);
    for (int off = 32; off; off >>= 1) s += __shfl_down(s, off);
    if (lane == 0) out[wid] = tanhf_(s * (1.0f / 128.0f));
}

extern "C" void kernel_launch(void* const* d_in, const int* in_sizes, int n_in,
                              void* d_out, int out_size, void* d_ws, size_t ws_size,
                              hipStream_t stream) {
    const float* x = (const float*)d_in[0];
    const void* edges = d_in[1];
    const float* weight = (const float*)d_in[2];
    const float* w_ih = (const float*)d_in[3];
    const float* w_hh = (const float*)d_in[4];
    const float* b_ih = (const float*)d_in[5];
    const float* b_hh = (const float*)d_in[6];
    float* out = (float*)d_out;

    char* ws = (char*)d_ws;
    size_t off = 0;
    auto alloc = [&](size_t bytes) -> char* {
        char* p = ws + off;
        off += (bytes + 255) & ~(size_t)255;
        return p;
    };
    // total ws ~112 MB (proven-safe watermark from R4: 162.8 MB)
    int* flag = (int*)alloc(4);
    int* counts = (int*)alloc((size_t)NN * 4);
    int* cursor = (int*)alloc((size_t)NN * 4);
    int* rowptr = (int*)alloc((size_t)(NN + 1) * 4);
    int* csr_src = (int*)alloc((size_t)NE * 4);
    float* inv_den = (float*)alloc((size_t)NN * 4);
    int* bsum = (int*)alloc((size_t)SCAN_NB * 4);
    int* boff = (int*)alloc((size_t)SCAN_NB * 4);
    short* B1hi = (short*)alloc((size_t)3 * 65536 * 2);
    short* B1lo = (short*)alloc((size_t)3 * 65536 * 2);
    short* B2hi = (short*)alloc((size_t)3 * 32768 * 2);
    short* B2lo = (short*)alloc((size_t)3 * 32768 * 2);
    float* bvec = (float*)alloc(512 * 4);
    unsigned short* aghi = (unsigned short*)alloc((size_t)NN * CC * 2);
    unsigned short* aglo = (unsigned short*)alloc((size_t)NN * CC * 2);
    unsigned short* hhi = (unsigned short*)alloc((size_t)NN * CC * 2);
    unsigned short* hlo = (unsigned short*)alloc((size_t)NN * CC * 2);

    hipMemsetAsync(counts, 0, (size_t)NN * 4, stream);
    hipMemsetAsync(cursor, 0, (size_t)NN * 4, stream);

    k_detect<<<1, 64, 0, stream>>>((const int*)edges, flag);
    k_count<<<(NE + 255) / 256, 256, 0, stream>>>(edges, flag, counts);
    k_scan1<<<SCAN_NB, SCAN_B, 0, stream>>>(counts, bsum);
    k_scan2<<<1, 512, 0, stream>>>(bsum, boff);
    k_scan3<<<SCAN_NB, SCAN_B, 0, stream>>>(counts, boff, rowptr, inv_den);
    k_bucket<<<(NE + 255) / 256, 256, 0, stream>>>(edges, flag, rowptr, cursor, csr_src);
    int prep_threads = 2 * 3 * C3 * CC + 512;
    k_prep<<<(prep_threads + 255) / 256, 256, 0, stream>>>(weight, w_ih, w_hh, b_ih, b_hh,
                                                           B1hi, B1lo, B2hi, B2lo, bvec);
    k_cvt<<<(NN * CC) / 2048, 256, 0, stream>>>(x, hhi, hlo);

    const int gru_blocks = (NN + 63) / 64;  // 1563
    for (int i = 0; i < 3; i++) {
        k_agg<<<25000, 256, 0, stream>>>(hhi, aghi, aglo, rowptr, csr_src, inv_den);
        k_gru_mfma<<<gru_blocks, 512, 0, stream>>>(aghi, aglo, hhi, hlo,
                                                   B1hi + (size_t)i * 65536, B1lo + (size_t)i * 65536,
                                                   B2hi + (size_t)i * 32768, B2lo + (size_t)i * 32768,
                                                   bvec);
    }
    k_out<<<25000, 256, 0, stream>>>(hhi, hlo, out);
}

// Round 10
// 840.618 us; speedup vs baseline: 1.4681x; 1.0675x over previous
//
#include <hip/hip_runtime.h>
#include <math.h>

#define NN 100000
#define NE 1600000
#define CC 128
#define C3 384
#define SCAN_B 256
#define SCAN_NB ((NN + SCAN_B - 1) / SCAN_B)  // 391
#define NCOARSE ((NN + 255) / 256)            // 391 coarse buckets (dst>>8)

typedef __attribute__((ext_vector_type(4))) float f4;
typedef __attribute__((ext_vector_type(8))) short s8;

__device__ __forceinline__ float sigmoidf_(float x) { return 1.0f / (1.0f + __expf(-x)); }
__device__ __forceinline__ float tanhf_(float x) { return 2.0f / (1.0f + __expf(-2.0f * x)) - 1.0f; }

__device__ __forceinline__ short f2bf(float x) {
    unsigned u = __float_as_uint(x);
    unsigned r = (u + 0x7fffu + ((u >> 16) & 1u)) >> 16;
    return (short)r;
}
__device__ __forceinline__ float bf2f(short s) {
    return __uint_as_float(((unsigned)(unsigned short)s) << 16);
}

// ---- edge dtype detection ----
__global__ void k_detect(const int* __restrict__ edges, int* __restrict__ flag) {
    if (threadIdx.x == 0) {
        int allz = 1;
        for (int i = 0; i < 32; i++)
            if (edges[2 * i + 1] != 0) allz = 0;
        *flag = allz;  // 1 => int64 layout
    }
}

__device__ __forceinline__ int edge_val(const void* edges, int f, long long idx) {
    return f ? (int)((const long long*)edges)[idx] : ((const int*)edges)[idx];
}

__global__ void k_count(const void* __restrict__ edges, const int* __restrict__ flag,
                        int* __restrict__ counts) {
    int e = blockIdx.x * blockDim.x + threadIdx.x;
    if (e < NE) {
        int f = *flag;
        int d = edge_val(edges, f, (long long)NE + e);
        atomicAdd(&counts[d], 1);
    }
}

// ---- multi-block scan ----
__global__ void k_scan1(const int* __restrict__ counts, int* __restrict__ bsum) {
    __shared__ int red[4];
    int t = threadIdx.x;
    int i = blockIdx.x * SCAN_B + t;
    int v = (i < NN) ? counts[i] : 0;
#pragma unroll
    for (int off = 32; off; off >>= 1) v += __shfl_down(v, off);
    if ((t & 63) == 0) red[t >> 6] = v;
    __syncthreads();
    if (t == 0) bsum[blockIdx.x] = red[0] + red[1] + red[2] + red[3];
}

__global__ void k_scan2(const int* __restrict__ bsum, int* __restrict__ boff) {
    __shared__ int lds[512];
    int t = threadIdx.x;
    int v = (t < SCAN_NB) ? bsum[t] : 0;
    lds[t] = v;
    __syncthreads();
    for (int off = 1; off < 512; off <<= 1) {
        int u = (t >= off) ? lds[t - off] : 0;
        __syncthreads();
        lds[t] += u;
        __syncthreads();
    }
    if (t < SCAN_NB) boff[t] = lds[t] - v;  // exclusive
}

__global__ void k_scan3(const int* __restrict__ counts, const int* __restrict__ boff,
                        int* __restrict__ rowptr, float* __restrict__ inv_denom) {
    __shared__ int lds[SCAN_B];
    int t = threadIdx.x;
    int i = blockIdx.x * SCAN_B + t;
    int v = (i < NN) ? counts[i] : 0;
    lds[t] = v;
    __syncthreads();
    for (int off = 1; off < SCAN_B; off <<= 1) {
        int u = (t >= off) ? lds[t - off] : 0;
        __syncthreads();
        lds[t] += u;
        __syncthreads();
    }
    if (i < NN) {
        rowptr[i] = boff[blockIdx.x] + lds[t] - v;
        inv_denom[i] = 1.0f / (float)((v > 1) ? v : 1);
    }
    if (i == 0) rowptr[NN] = NE;
}

// coarse_cursor[c] = rowptr[256*c] (re-init every call; graph-safe)
__global__ void k_coarse_init(const int* __restrict__ rowptr, int* __restrict__ coarse_cursor) {
    int c = threadIdx.x + blockIdx.x * blockDim.x;
    if (c < NCOARSE) coarse_cursor[c] = rowptr[c * 256];
}

// ---- CSR build phase 1: partition edges into coarse-bucket-grouped (src,dst) pairs ----
// 1024 thr x 8 edges = 8192 edges/block. tmp region for bucket c = CSR segment
// [rowptr[256c], rowptr[256(c+1)]) -- contiguous; block writes runs of ~21 pairs.
__global__ __launch_bounds__(1024) void k_part(const void* __restrict__ edges,
                                               const int* __restrict__ flag,
                                               int* __restrict__ coarse_cursor,
                                               uint2* __restrict__ tmp) {
    __shared__ int hist[NCOARSE];
    __shared__ int base[NCOARSE];
    int t = threadIdx.x;
    long long e0 = (long long)blockIdx.x * 8192;
    int f = *flag;

    for (int c = t; c < NCOARSE; c += 1024) hist[c] = 0;
    __syncthreads();

    int src[8], dst[8];
#pragma unroll
    for (int i = 0; i < 8; i++) {
        long long e = e0 + i * 1024 + t;
        if (e < NE) {
            src[i] = edge_val(edges, f, e);
            dst[i] = edge_val(edges, f, NE + e);
            atomicAdd(&hist[dst[i] >> 8], 1);
        } else {
            dst[i] = -1;
        }
    }
    __syncthreads();
    for (int c = t; c < NCOARSE; c += 1024) {
        int h = hist[c];
        base[c] = (h > 0) ? atomicAdd(&coarse_cursor[c], h) : 0;
        hist[c] = 0;
    }
    __syncthreads();
#pragma unroll
    for (int i = 0; i < 8; i++) {
        if (dst[i] >= 0) {
            int c = dst[i] >> 8;
            int off = atomicAdd(&hist[c], 1);
            tmp[base[c] + off] = make_uint2((unsigned)src[i], (unsigned)dst[i]);
        }
    }
}

// ---- CSR build phase 2: per coarse bucket, scatter src into its contiguous csr region ----
// One block per bucket; writes confined to ~16 KB region on one XCD -> writes ~= logical.
__global__ void k_fine(const uint2* __restrict__ tmp, const int* __restrict__ rowptr,
                       int* __restrict__ csr_src) {
    __shared__ int cur[256];
    int c = blockIdx.x;
    int t = threadIdx.x;
    int d = c * 256 + t;
    cur[t] = (d <= NN) ? rowptr[d < NN ? d : NN] : NE;
    __syncthreads();
    int start = rowptr[c * 256];
    int endd = (c * 256 + 256 <= NN) ? rowptr[c * 256 + 256] : NE;
    for (int p = start + t; p < endd; p += 256) {
        uint2 pr = tmp[p];
        int slot = atomicAdd(&cur[pr.y & 255], 1);
        csr_src[slot] = (int)pr.x;
    }
}

// ---- weight prep (validated R2) ----
__global__ void k_prep(const float* __restrict__ weight, const float* __restrict__ w_ih,
                       const float* __restrict__ w_hh, const float* __restrict__ b_ih,
                       const float* __restrict__ b_hh,
                       short* __restrict__ B1hi, short* __restrict__ B1lo,
                       short* __restrict__ B2hi, short* __restrict__ B2lo,
                       float* __restrict__ bvec) {
    const int P1 = 3 * C3 * CC;
    int gid = blockIdx.x * blockDim.x + threadIdx.x;
    if (gid < P1) {
        int i = gid / (C3 * CC);
        int rem = gid % (C3 * CC);
        int j = rem / CC;
        int k = rem % CC;
        const float* Wr = weight + i * CC * CC + k * CC;
        const float* ir = w_ih + j * CC;
        float v = 0.f;
#pragma unroll 4
        for (int c = 0; c < CC; c++) v += Wr[c] * ir[c];
        short hi = f2bf(v);
        short lo = f2bf(v - bf2f(hi));
        if (j < 256) {
            int idx = i * 65536 + j * 256 + k;
            B1hi[idx] = hi; B1lo[idx] = lo;
        } else {
            int idx = i * 32768 + (j - 256) * 128 + k;
            B2hi[idx] = hi; B2lo[idx] = lo;
        }
    } else if (gid < 2 * P1) {
        int g = gid - P1;
        int i = g / (C3 * CC);
        int rem = g % (C3 * CC);
        int j = rem / CC;
        int k = rem % CC;
        float v = w_hh[j * CC + k];
        short hi = f2bf(v);
        short lo = f2bf(v - bf2f(hi));
        if (j < 256) {
            int idx = i * 65536 + j * 256 + 128 + k;
            B1hi[idx] = hi; B1lo[idx] = lo;
        } else {
            int idx = i * 32768 + (j - 256 + 128) * 128 + k;
            B2hi[idx] = hi; B2lo[idx] = lo;
        }
    } else if (gid < 2 * P1 + 512) {
        int j = gid - 2 * P1;
        float v;
        if (j < 256) v = b_ih[j] + b_hh[j];
        else if (j < 384) v = b_ih[j];
        else v = b_hh[j - 128];
        bvec[j] = v;
    }
}

// ---- x -> split-bf16 dense hhi/hlo ----
__global__ void k_cvt(const float* __restrict__ x, unsigned short* __restrict__ hhi,
                      unsigned short* __restrict__ hlo) {
    long long g = ((long long)blockIdx.x * 256 + threadIdx.x) * 8;
    float4 v0 = *(const float4*)(x + g);
    float4 v1 = *(const float4*)(x + g + 4);
    float f[8] = {v0.x, v0.y, v0.z, v0.w, v1.x, v1.y, v1.z, v1.w};
    s8 oh, ol;
#pragma unroll
    for (int q = 0; q < 8; q++) {
        short hi = f2bf(f[q]);
        oh[q] = hi;
        ol[q] = f2bf(f[q] - bf2f(hi));
    }
    *(s8*)(hhi + g) = oh;
    *(s8*)(hlo + g) = ol;
}

// ---- aggregation: gather bf16 hhi (256 B dense rows); write split-bf16 a_hat dense ----
__global__ void k_agg(const unsigned short* __restrict__ hhi,
                      unsigned short* __restrict__ aghi, unsigned short* __restrict__ aglo,
                      const int* __restrict__ rowptr, const int* __restrict__ csr_src,
                      const float* __restrict__ inv_denom) {
    int wid = (blockIdx.x * blockDim.x + threadIdx.x) >> 6;
    int lane = threadIdx.x & 63;
    if (wid >= NN) return;
    int lo = rowptr[wid], hi = rowptr[wid + 1];
    int half = lane >> 5;
    int l32 = lane & 31;
    float a0 = 0.f, a1 = 0.f, a2 = 0.f, a3 = 0.f;
    for (int e = lo + half; e < hi; e += 2) {
        int s = csr_src[e];
        ushort4 v = ((const ushort4*)(hhi + (long long)s * CC))[l32];
        a0 += bf2f((short)v.x);
        a1 += bf2f((short)v.y);
        a2 += bf2f((short)v.z);
        a3 += bf2f((short)v.w);
    }
    a0 += __shfl_down(a0, 32);
    a1 += __shfl_down(a1, 32);
    a2 += __shfl_down(a2, 32);
    a3 += __shfl_down(a3, 32);
    if (half == 0) {
        float inv = inv_denom[wid];
        float s[4] = {a0 * inv, a1 * inv, a2 * inv, a3 * inv};
        ushort4 vh, vl;
        short h0 = f2bf(s[0]); vh.x = (unsigned short)h0; vl.x = (unsigned short)f2bf(s[0] - bf2f(h0));
        short h1 = f2bf(s[1]); vh.y = (unsigned short)h1; vl.y = (unsigned short)f2bf(s[1] - bf2f(h1));
        short h2 = f2bf(s[2]); vh.z = (unsigned short)h2; vl.z = (unsigned short)f2bf(s[2] - bf2f(h2));
        short h3 = f2bf(s[3]); vh.w = (unsigned short)h3; vl.w = (unsigned short)f2bf(s[3] - bf2f(h3));
        ((ushort4*)(aghi + (long long)wid * CC))[l32] = vh;
        ((ushort4*)(aglo + (long long)wid * CC))[l32] = vl;
    }
}

// ---- fused split-bf16 MFMA GEMM + GRU (validated R9: 64 nodes, 8 waves, 2 blk/CU) ----
__global__ __launch_bounds__(512, 4) void k_gru_mfma(
    const unsigned short* __restrict__ aghi, const unsigned short* __restrict__ aglo,
    unsigned short* __restrict__ hhi, unsigned short* __restrict__ hlo,
    const short* __restrict__ B1hi, const short* __restrict__ B1lo,
    const short* __restrict__ B2hi, const short* __restrict__ B2lo,
    const float* __restrict__ bvec) {
    __shared__ short Ahi[16384];
    __shared__ short Alo[16384];
    int t = threadIdx.x;
    long long nb = (long long)blockIdx.x * 64;

#pragma unroll
    for (int half = 0; half < 2; half++) {
        const unsigned short* sh = half ? hhi : aghi;
        const unsigned short* sl = half ? hlo : aglo;
#pragma unroll
        for (int i = 0; i < 2; i++) {
            int ci = t + 512 * i;
            int rr = ci >> 4;
            int c = ci & 15;
            int c4 = half * 16 + c;
            long long row = nb + rr;
            if (row >= NN) row = NN - 1;
            int off = (c4 >> 2) * 2048 + (rr >> 4) * 512 + (rr & 15) * 32 + (c4 & 3) * 8;
            long long gsrc = row * CC + c * 8;
            *(s8*)&Ahi[off] = *(const s8*)(sh + gsrc);
            *(s8*)&Alo[off] = *(const s8*)(sl + gsrc);
        }
    }
    __syncthreads();

    int wv = t >> 6;
    int L = t & 63;
    int lm = L & 15;
    int lq = L >> 4;
    int j = wv * 16 + lm;

    f4 aR[4], aZ[4], aN[4], aH[4];
    {
        float bR = bvec[j], bZ = bvec[128 + j], bN = bvec[256 + j], bH = bvec[384 + j];
#pragma unroll
        for (int ch = 0; ch < 4; ch++) {
            aR[ch] = (f4){bR, bR, bR, bR};
            aZ[ch] = (f4){bZ, bZ, bZ, bZ};
            aN[ch] = (f4){bN, bN, bN, bN};
            aH[ch] = (f4){bH, bH, bH, bH};
        }
    }

#pragma unroll
    for (int ks = 0; ks < 8; ks++) {
        int o1 = ks * 32 + lq * 8;
        s8 bRh = *(const s8*)(B1hi + j * 256 + o1);
        s8 bRl = *(const s8*)(B1lo + j * 256 + o1);
        s8 bZh = *(const s8*)(B1hi + (128 + j) * 256 + o1);
        s8 bZl = *(const s8*)(B1lo + (128 + j) * 256 + o1);
        int rowG = (ks < 4) ? j : (128 + j);
        int o2 = (ks & 3) * 32 + lq * 8;
        s8 bGh = *(const s8*)(B2hi + rowG * 128 + o2);
        s8 bGl = *(const s8*)(B2lo + rowG * 128 + o2);
#pragma unroll
        for (int ch = 0; ch < 4; ch++) {
            int aoff = ks * 2048 + ch * 512 + lm * 32 + lq * 8;
            s8 ah = *(const s8*)&Ahi[aoff];
            s8 al = *(const s8*)&Alo[aoff];
            aR[ch] = __builtin_amdgcn_mfma_f32_16x16x32_bf16(ah, bRh, aR[ch], 0, 0, 0);
            aR[ch] = __builtin_amdgcn_mfma_f32_16x16x32_bf16(al, bRh, aR[ch], 0, 0, 0);
            aR[ch] = __builtin_amdgcn_mfma_f32_16x16x32_bf16(ah, bRl, aR[ch], 0, 0, 0);
            aZ[ch] = __builtin_amdgcn_mfma_f32_16x16x32_bf16(ah, bZh, aZ[ch], 0, 0, 0);
            aZ[ch] = __builtin_amdgcn_mfma_f32_16x16x32_bf16(al, bZh, aZ[ch], 0, 0, 0);
            aZ[ch] = __builtin_amdgcn_mfma_f32_16x16x32_bf16(ah, bZl, aZ[ch], 0, 0, 0);
            if (ks < 4) {
                aN[ch] = __builtin_amdgcn_mfma_f32_16x16x32_bf16(ah, bGh, aN[ch], 0, 0, 0);
                aN[ch] = __builtin_amdgcn_mfma_f32_16x16x32_bf16(al, bGh, aN[ch], 0, 0, 0);
                aN[ch] = __builtin_amdgcn_mfma_f32_16x16x32_bf16(ah, bGl, aN[ch], 0, 0, 0);
            } else {
                aH[ch] = __builtin_amdgcn_mfma_f32_16x16x32_bf16(ah, bGh, aH[ch], 0, 0, 0);
                aH[ch] = __builtin_amdgcn_mfma_f32_16x16x32_bf16(al, bGh, aH[ch], 0, 0, 0);
                aH[ch] = __builtin_amdgcn_mfma_f32_16x16x32_bf16(ah, bGl, aH[ch], 0, 0, 0);
            }
        }
    }

    {
        int c4 = 16 + (j >> 3);
        int obase = (c4 >> 2) * 2048 + (c4 & 3) * 8 + (j & 7);
#pragma unroll
        for (int ch = 0; ch < 4; ch++) {
#pragma unroll
            for (int r = 0; r < 4; r++) {
                int node = ch * 16 + lq * 4 + r;
                int off = obase + ch * 512 + (node & 15) * 32;
                float hp = bf2f(Ahi[off]) + bf2f(Alo[off]);
                float sr = aR[ch][r];
                float sz = aZ[ch][r];
                float in_ = aN[ch][r];
                float hn = aH[ch][r];
                float rg = sigmoidf_(sr);
                float zg = sigmoidf_(sz);
                float nv = tanhf_(in_ + rg * hn);
                float val = (1.f - zg) * nv + zg * hp;
                long long gnode = nb + node;
                if (gnode < NN) {
                    long long gd = gnode * CC + j;
                    short vh = f2bf(val);
                    hhi[gd] = (unsigned short)vh;
                    hlo[gd] = (unsigned short)f2bf(val - bf2f(vh));
                }
            }
        }
    }
}

// ---- out[n] = tanh(mean_c (hi+lo)) ----
__global__ void k_out(const unsigned short* __restrict__ hhi,
                      const unsigned short* __restrict__ hlo, float* __restrict__ out) {
    int wid = (blockIdx.x * blockDim.x + threadIdx.x) >> 6;
    int lane = threadIdx.x & 63;
    if (wid >= NN) return;
    ushort2 vh = ((const ushort2*)(hhi + (long long)wid * CC))[lane];
    ushort2 vl = ((const ushort2*)(hlo + (long long)wid * CC))[lane];
    float s = bf2f((short)vh.x) + bf2f((short)vl.x) + bf2f((short)vh.y) + bf2f((short)vl.y);
    for (int off = 32; off; off >>= 1) s += __shfl_down(s, off);
    if (lane == 0) out[wid] = tanhf_(s * (1.0f / 128.0f));
}

extern "C" void kernel_launch(void* const* d_in, const int* in_sizes, int n_in,
                              void* d_out, int out_size, void* d_ws, size_t ws_size,
                              hipStream_t stream) {
    const float* x = (const float*)d_in[0];
    const void* edges = d_in[1];
    const float* weight = (const float*)d_in[2];
    const float* w_ih = (const float*)d_in[3];
    const float* w_hh = (const float*)d_in[4];
    const float* b_ih = (const float*)d_in[5];
    const float* b_hh = (const float*)d_in[6];
    float* out = (float*)d_out;

    char* ws = (char*)d_ws;
    size_t off = 0;
    auto alloc = [&](size_t bytes) -> char* {
        char* p = ws + off;
        off += (bytes + 255) & ~(size_t)255;
        return p;
    };
    // total ws ~125 MB (proven-safe watermark from R4: 162.8 MB)
    int* flag = (int*)alloc(4);
    int* counts = (int*)alloc((size_t)NN * 4);
    int* rowptr = (int*)alloc((size_t)(NN + 1) * 4);
    int* csr_src = (int*)alloc((size_t)NE * 4);
    float* inv_den = (float*)alloc((size_t)NN * 4);
    int* bsum = (int*)alloc((size_t)SCAN_NB * 4);
    int* boff = (int*)alloc((size_t)SCAN_NB * 4);
    int* coarse_cursor = (int*)alloc((size_t)NCOARSE * 4);
    uint2* tmp = (uint2*)alloc((size_t)NE * 8);
    short* B1hi = (short*)alloc((size_t)3 * 65536 * 2);
    short* B1lo = (short*)alloc((size_t)3 * 65536 * 2);
    short* B2hi = (short*)alloc((size_t)3 * 32768 * 2);
    short* B2lo = (short*)alloc((size_t)3 * 32768 * 2);
    float* bvec = (float*)alloc(512 * 4);
    unsigned short* aghi = (unsigned short*)alloc((size_t)NN * CC * 2);
    unsigned short* aglo = (unsigned short*)alloc((size_t)NN * CC * 2);
    unsigned short* hhi = (unsigned short*)alloc((size_t)NN * CC * 2);
    unsigned short* hlo = (unsigned short*)alloc((size_t)NN * CC * 2);

    hipMemsetAsync(counts, 0, (size_t)NN * 4, stream);

    k_detect<<<1, 64, 0, stream>>>((const int*)edges, flag);
    k_count<<<(NE + 255) / 256, 256, 0, stream>>>(edges, flag, counts);
    k_scan1<<<SCAN_NB, SCAN_B, 0, stream>>>(counts, bsum);
    k_scan2<<<1, 512, 0, stream>>>(bsum, boff);
    k_scan3<<<SCAN_NB, SCAN_B, 0, stream>>>(counts, boff, rowptr, inv_den);
    k_coarse_init<<<2, 256, 0, stream>>>(rowptr, coarse_cursor);
    k_part<<<(NE + 8191) / 8192, 1024, 0, stream>>>(edges, flag, coarse_cursor, tmp);
    k_fine<<<NCOARSE, 256, 0, stream>>>(tmp, rowptr, csr_src);
    int prep_threads = 2 * 3 * C3 * CC + 512;
    k_prep<<<(prep_threads + 255) / 256, 256, 0, stream>>>(weight, w_ih, w_hh, b_ih, b_hh,
                                                           B1hi, B1lo, B2hi, B2lo, bvec);
    k_cvt<<<(NN * CC) / 2048, 256, 0, stream>>>(x, hhi, hlo);

    const int gru_blocks = (NN + 63) / 64;  // 1563
    for (int i = 0; i < 3; i++) {
        k_agg<<<25000, 256, 0, stream>>>(hhi, aghi, aglo, rowptr, csr_src, inv_den);
        k_gru_mfma<<<gru_blocks, 512, 0, stream>>>(aghi, aglo, hhi, hlo,
                                                   B1hi + (size_t)i * 65536, B1lo + (size_t)i * 65536,
                                                   B2hi + (size_t)i * 32768, B2lo + (size_t)i * 32768,
                                                   bvec);
    }
    k_out<<<25000, 256, 0, stream>>>(hhi, hlo, out);
}

// Round 11
// 745.768 us; speedup vs baseline: 1.6548x; 1.1272x over previous
//
#include <hip/hip_runtime.h>
#include <math.h>

#define NN 100000
#define NE 1600000
#define CC 128
#define C3 384
#define SCAN_B 256
#define SCAN_NB ((NN + SCAN_B - 1) / SCAN_B)  // 391 (also = coarse bucket count)

typedef __attribute__((ext_vector_type(4))) float f4;
typedef __attribute__((ext_vector_type(8))) short s8;

__device__ __forceinline__ float sigmoidf_(float x) { return 1.0f / (1.0f + __expf(-x)); }
__device__ __forceinline__ float tanhf_(float x) { return 2.0f / (1.0f + __expf(-2.0f * x)) - 1.0f; }

__device__ __forceinline__ short f2bf(float x) {
    unsigned u = __float_as_uint(x);
    unsigned r = (u + 0x7fffu + ((u >> 16) & 1u)) >> 16;
    return (short)r;
}
__device__ __forceinline__ float bf2f(short s) {
    return __uint_as_float(((unsigned)(unsigned short)s) << 16);
}

// ---- edge dtype: int64 => all odd int32 words zero. Computed per-block (L1-cached). ----
__device__ __forceinline__ int detect_flag(const int* e32) {
    int allz = 1;
#pragma unroll
    for (int i = 0; i < 32; i++)
        if (e32[2 * i + 1] != 0) allz = 0;
    return allz;
}

__device__ __forceinline__ int edge_val(const void* edges, int f, long long idx) {
    return f ? (int)((const long long*)edges)[idx] : ((const int*)edges)[idx];
}

__global__ void k_count(const void* __restrict__ edges, int* __restrict__ counts) {
    __shared__ int sf;
    if (threadIdx.x == 0) sf = detect_flag((const int*)edges);
    __syncthreads();
    int f = sf;
    int e = blockIdx.x * blockDim.x + threadIdx.x;
    if (e < NE) {
        int d = edge_val(edges, f, (long long)NE + e);
        atomicAdd(&counts[d], 1);
    }
}

// ---- multi-block scan ----
__global__ void k_scan1(const int* __restrict__ counts, int* __restrict__ bsum) {
    __shared__ int red[4];
    int t = threadIdx.x;
    int i = blockIdx.x * SCAN_B + t;
    int v = (i < NN) ? counts[i] : 0;
#pragma unroll
    for (int off = 32; off; off >>= 1) v += __shfl_down(v, off);
    if ((t & 63) == 0) red[t >> 6] = v;
    __syncthreads();
    if (t == 0) bsum[blockIdx.x] = red[0] + red[1] + red[2] + red[3];
}

// scan2 also writes coarse_cursor: rowptr[256c] == boff[c] (local prefix is 0 there)
__global__ void k_scan2(const int* __restrict__ bsum, int* __restrict__ boff,
                        int* __restrict__ coarse_cursor) {
    __shared__ int lds[512];
    int t = threadIdx.x;
    int v = (t < SCAN_NB) ? bsum[t] : 0;
    lds[t] = v;
    __syncthreads();
    for (int off = 1; off < 512; off <<= 1) {
        int u = (t >= off) ? lds[t - off] : 0;
        __syncthreads();
        lds[t] += u;
        __syncthreads();
    }
    if (t < SCAN_NB) {
        int ex = lds[t] - v;
        boff[t] = ex;
        coarse_cursor[t] = ex;
    }
}

__global__ void k_scan3(const int* __restrict__ counts, const int* __restrict__ boff,
                        int* __restrict__ rowptr, float* __restrict__ inv_denom) {
    __shared__ int lds[SCAN_B];
    int t = threadIdx.x;
    int i = blockIdx.x * SCAN_B + t;
    int v = (i < NN) ? counts[i] : 0;
    lds[t] = v;
    __syncthreads();
    for (int off = 1; off < SCAN_B; off <<= 1) {
        int u = (t >= off) ? lds[t - off] : 0;
        __syncthreads();
        lds[t] += u;
        __syncthreads();
    }
    if (i < NN) {
        rowptr[i] = boff[blockIdx.x] + lds[t] - v;
        inv_denom[i] = 1.0f / (float)((v > 1) ? v : 1);
    }
    if (i == 0) rowptr[NN] = NE;
}

// ---- CSR build phase 1: partition into coarse-bucket-grouped (src,dst) pairs ----
__global__ __launch_bounds__(1024) void k_part(const void* __restrict__ edges,
                                               int* __restrict__ coarse_cursor,
                                               uint2* __restrict__ tmp) {
    __shared__ int hist[SCAN_NB];
    __shared__ int base[SCAN_NB];
    __shared__ int sf;
    int t = threadIdx.x;
    if (t == 0) sf = detect_flag((const int*)edges);
    long long e0 = (long long)blockIdx.x * 8192;

    for (int c = t; c < SCAN_NB; c += 1024) hist[c] = 0;
    __syncthreads();
    int f = sf;

    int src[8], dst[8];
#pragma unroll
    for (int i = 0; i < 8; i++) {
        long long e = e0 + i * 1024 + t;
        if (e < NE) {
            src[i] = edge_val(edges, f, e);
            dst[i] = edge_val(edges, f, NE + e);
            atomicAdd(&hist[dst[i] >> 8], 1);
        } else {
            dst[i] = -1;
        }
    }
    __syncthreads();
    for (int c = t; c < SCAN_NB; c += 1024) {
        int h = hist[c];
        base[c] = (h > 0) ? atomicAdd(&coarse_cursor[c], h) : 0;
        hist[c] = 0;
    }
    __syncthreads();
#pragma unroll
    for (int i = 0; i < 8; i++) {
        if (dst[i] >= 0) {
            int c = dst[i] >> 8;
            int off = atomicAdd(&hist[c], 1);
            tmp[base[c] + off] = make_uint2((unsigned)src[i], (unsigned)dst[i]);
        }
    }
}

// ---- CSR build phase 2: per coarse bucket, scatter into its contiguous csr region ----
__global__ void k_fine(const uint2* __restrict__ tmp, const int* __restrict__ rowptr,
                       int* __restrict__ csr_src) {
    __shared__ int cur[256];
    int c = blockIdx.x;
    int t = threadIdx.x;
    int d = c * 256 + t;
    cur[t] = (d <= NN) ? rowptr[d < NN ? d : NN] : NE;
    __syncthreads();
    int start = rowptr[c * 256];
    int endd = (c * 256 + 256 <= NN) ? rowptr[c * 256 + 256] : NE;
    for (int p = start + t; p < endd; p += 256) {
        uint2 pr = tmp[p];
        int slot = atomicAdd(&cur[pr.y & 255], 1);
        csr_src[slot] = (int)pr.x;
    }
}

// ---- weight prep (validated R2) ----
__global__ void k_prep(const float* __restrict__ weight, const float* __restrict__ w_ih,
                       const float* __restrict__ w_hh, const float* __restrict__ b_ih,
                       const float* __restrict__ b_hh,
                       short* __restrict__ B1hi, short* __restrict__ B1lo,
                       short* __restrict__ B2hi, short* __restrict__ B2lo,
                       float* __restrict__ bvec) {
    const int P1 = 3 * C3 * CC;
    int gid = blockIdx.x * blockDim.x + threadIdx.x;
    if (gid < P1) {
        int i = gid / (C3 * CC);
        int rem = gid % (C3 * CC);
        int j = rem / CC;
        int k = rem % CC;
        const float* Wr = weight + i * CC * CC + k * CC;
        const float* ir = w_ih + j * CC;
        float v = 0.f;
#pragma unroll 4
        for (int c = 0; c < CC; c++) v += Wr[c] * ir[c];
        short hi = f2bf(v);
        short lo = f2bf(v - bf2f(hi));
        if (j < 256) {
            int idx = i * 65536 + j * 256 + k;
            B1hi[idx] = hi; B1lo[idx] = lo;
        } else {
            int idx = i * 32768 + (j - 256) * 128 + k;
            B2hi[idx] = hi; B2lo[idx] = lo;
        }
    } else if (gid < 2 * P1) {
        int g = gid - P1;
        int i = g / (C3 * CC);
        int rem = g % (C3 * CC);
        int j = rem / CC;
        int k = rem % CC;
        float v = w_hh[j * CC + k];
        short hi = f2bf(v);
        short lo = f2bf(v - bf2f(hi));
        if (j < 256) {
            int idx = i * 65536 + j * 256 + 128 + k;
            B1hi[idx] = hi; B1lo[idx] = lo;
        } else {
            int idx = i * 32768 + (j - 256 + 128) * 128 + k;
            B2hi[idx] = hi; B2lo[idx] = lo;
        }
    } else if (gid < 2 * P1 + 512) {
        int j = gid - 2 * P1;
        float v;
        if (j < 256) v = b_ih[j] + b_hh[j];
        else if (j < 384) v = b_ih[j];
        else v = b_hh[j - 128];
        bvec[j] = v;
    }
}

// ---- x -> split-bf16 dense hhi/hlo ----
__global__ void k_cvt(const float* __restrict__ x, unsigned short* __restrict__ hhi,
                      unsigned short* __restrict__ hlo) {
    long long g = ((long long)blockIdx.x * 256 + threadIdx.x) * 8;
    float4 v0 = *(const float4*)(x + g);
    float4 v1 = *(const float4*)(x + g + 4);
    float f[8] = {v0.x, v0.y, v0.z, v0.w, v1.x, v1.y, v1.z, v1.w};
    s8 oh, ol;
#pragma unroll
    for (int q = 0; q < 8; q++) {
        short hi = f2bf(f[q]);
        oh[q] = hi;
        ol[q] = f2bf(f[q] - bf2f(hi));
    }
    *(s8*)(hhi + g) = oh;
    *(s8*)(hlo + g) = ol;
}

// ---- FUSED layer: gather+mean (into LDS) -> split-bf16 MFMA GEMM -> GRU -> h_out ----
// 64 nodes/block, 512 threads = 8 waves (R9/R10-validated GEMM shape).
// Gather: quarter-wave (16 lanes x 16 B) reads one full bf16 row per edge; 4 nodes
// in flight per wave x 2-edge unroll = 8 outstanding 256 B loads/wave. a_hat is
// split to bf16 hi/lo and written straight into the LDS A-fragment slots (no
// global a_hat round-trip). h double-buffered: reads h_i, writes h_o (no race).
// LDS frag order (shorts): off = (c4>>2)*2048 + (rr>>4)*512 + (rr&15)*32 + (c4&3)*8.
__global__ __launch_bounds__(512, 4) void k_fused(
    const unsigned short* __restrict__ hhi_i, const unsigned short* __restrict__ hlo_i,
    unsigned short* __restrict__ hhi_o, unsigned short* __restrict__ hlo_o,
    const int* __restrict__ rowptr, const int* __restrict__ csr_src,
    const float* __restrict__ inv_denom,
    const short* __restrict__ B1hi, const short* __restrict__ B1lo,
    const short* __restrict__ B2hi, const short* __restrict__ B2lo,
    const float* __restrict__ bvec) {
    __shared__ short Ahi[16384];
    __shared__ short Alo[16384];
    int t = threadIdx.x;
    long long nb = (long long)blockIdx.x * 64;
    int wv = t >> 6;
    int L = t & 63;

    // stage h half (cols 128..255) from h_i: branch-free s8 copies
#pragma unroll
    for (int i = 0; i < 2; i++) {
        int ci = t + 512 * i;        // 0..1023 = 64 rows x 16 chunks
        int rr = ci >> 4;
        int c = ci & 15;
        int c4 = 16 + c;
        long long row = nb + rr;
        if (row >= NN) row = NN - 1;
        int off = (c4 >> 2) * 2048 + (rr >> 4) * 512 + (rr & 15) * 32 + (c4 & 3) * 8;
        long long gsrc = row * CC + c * 8;
        *(s8*)&Ahi[off] = *(const s8*)(hhi_i + gsrc);
        *(s8*)&Alo[off] = *(const s8*)(hlo_i + gsrc);
    }

    // gather + mean into A cols 0..127: quarter-wave per node, 2 passes of 4 nodes
    {
        int q = L >> 4;
        int l16 = L & 15;
#pragma unroll
        for (int pass = 0; pass < 2; pass++) {
            int rr = wv * 8 + pass * 4 + q;          // local row 0..63
            long long rowc = nb + rr;
            if (rowc >= NN) rowc = NN - 1;
            int lo = rowptr[rowc], hi = rowptr[rowc + 1];
            float acc0[8] = {0, 0, 0, 0, 0, 0, 0, 0};
            float acc1[8] = {0, 0, 0, 0, 0, 0, 0, 0};
            int e = lo;
            for (; e + 1 < hi; e += 2) {
                int s0 = csr_src[e];
                int s1 = csr_src[e + 1];
                s8 v0 = ((const s8*)(hhi_i + (long long)s0 * CC))[l16];
                s8 v1 = ((const s8*)(hhi_i + (long long)s1 * CC))[l16];
#pragma unroll
                for (int k = 0; k < 8; k++) {
                    acc0[k] += bf2f(v0[k]);
                    acc1[k] += bf2f(v1[k]);
                }
            }
            if (e < hi) {
                int s0 = csr_src[e];
                s8 v0 = ((const s8*)(hhi_i + (long long)s0 * CC))[l16];
#pragma unroll
                for (int k = 0; k < 8; k++) acc0[k] += bf2f(v0[k]);
            }
            float inv = inv_denom[rowc];
            s8 vh, vl;
#pragma unroll
            for (int k = 0; k < 8; k++) {
                float f = (acc0[k] + acc1[k]) * inv;
                short hi16 = f2bf(f);
                vh[k] = hi16;
                vl[k] = f2bf(f - bf2f(hi16));
            }
            int off = (l16 >> 2) * 2048 + (rr >> 4) * 512 + (rr & 15) * 32 + (l16 & 3) * 8;
            *(s8*)&Ahi[off] = vh;
            *(s8*)&Alo[off] = vl;
        }
    }
    __syncthreads();

    int lm = L & 15;
    int lq = L >> 4;
    int j = wv * 16 + lm;

    f4 aR[4], aZ[4], aN[4], aH[4];
    {
        float bR = bvec[j], bZ = bvec[128 + j], bN = bvec[256 + j], bH = bvec[384 + j];
#pragma unroll
        for (int ch = 0; ch < 4; ch++) {
            aR[ch] = (f4){bR, bR, bR, bR};
            aZ[ch] = (f4){bZ, bZ, bZ, bZ};
            aN[ch] = (f4){bN, bN, bN, bN};
            aH[ch] = (f4){bH, bH, bH, bH};
        }
    }

#pragma unroll
    for (int ks = 0; ks < 8; ks++) {
        int o1 = ks * 32 + lq * 8;
        s8 bRh = *(const s8*)(B1hi + j * 256 + o1);
        s8 bRl = *(const s8*)(B1lo + j * 256 + o1);
        s8 bZh = *(const s8*)(B1hi + (128 + j) * 256 + o1);
        s8 bZl = *(const s8*)(B1lo + (128 + j) * 256 + o1);
        int rowG = (ks < 4) ? j : (128 + j);
        int o2 = (ks & 3) * 32 + lq * 8;
        s8 bGh = *(const s8*)(B2hi + rowG * 128 + o2);
        s8 bGl = *(const s8*)(B2lo + rowG * 128 + o2);
#pragma unroll
        for (int ch = 0; ch < 4; ch++) {
            int aoff = ks * 2048 + ch * 512 + lm * 32 + lq * 8;
            s8 ah = *(const s8*)&Ahi[aoff];
            s8 al = *(const s8*)&Alo[aoff];
            aR[ch] = __builtin_amdgcn_mfma_f32_16x16x32_bf16(ah, bRh, aR[ch], 0, 0, 0);
            aR[ch] = __builtin_amdgcn_mfma_f32_16x16x32_bf16(al, bRh, aR[ch], 0, 0, 0);
            aR[ch] = __builtin_amdgcn_mfma_f32_16x16x32_bf16(ah, bRl, aR[ch], 0, 0, 0);
            aZ[ch] = __builtin_amdgcn_mfma_f32_16x16x32_bf16(ah, bZh, aZ[ch], 0, 0, 0);
            aZ[ch] = __builtin_amdgcn_mfma_f32_16x16x32_bf16(al, bZh, aZ[ch], 0, 0, 0);
            aZ[ch] = __builtin_amdgcn_mfma_f32_16x16x32_bf16(ah, bZl, aZ[ch], 0, 0, 0);
            if (ks < 4) {
                aN[ch] = __builtin_amdgcn_mfma_f32_16x16x32_bf16(ah, bGh, aN[ch], 0, 0, 0);
                aN[ch] = __builtin_amdgcn_mfma_f32_16x16x32_bf16(al, bGh, aN[ch], 0, 0, 0);
                aN[ch] = __builtin_amdgcn_mfma_f32_16x16x32_bf16(ah, bGl, aN[ch], 0, 0, 0);
            } else {
                aH[ch] = __builtin_amdgcn_mfma_f32_16x16x32_bf16(ah, bGh, aH[ch], 0, 0, 0);
                aH[ch] = __builtin_amdgcn_mfma_f32_16x16x32_bf16(al, bGh, aH[ch], 0, 0, 0);
                aH[ch] = __builtin_amdgcn_mfma_f32_16x16x32_bf16(ah, bGl, aH[ch], 0, 0, 0);
            }
        }
    }

    // register-only GRU epilogue -> h_o (double buffer; no in-place race)
    {
        int c4 = 16 + (j >> 3);
        int obase = (c4 >> 2) * 2048 + (c4 & 3) * 8 + (j & 7);
#pragma unroll
        for (int ch = 0; ch < 4; ch++) {
#pragma unroll
            for (int r = 0; r < 4; r++) {
                int node = ch * 16 + lq * 4 + r;
                int off = obase + ch * 512 + (node & 15) * 32;
                float hp = bf2f(Ahi[off]) + bf2f(Alo[off]);
                float sr = aR[ch][r];
                float sz = aZ[ch][r];
                float in_ = aN[ch][r];
                float hn = aH[ch][r];
                float rg = sigmoidf_(sr);
                float zg = sigmoidf_(sz);
                float nv = tanhf_(in_ + rg * hn);
                float val = (1.f - zg) * nv + zg * hp;
                long long gnode = nb + node;
                if (gnode < NN) {
                    long long gd = gnode * CC + j;
                    short vh = f2bf(val);
                    hhi_o[gd] = (unsigned short)vh;
                    hlo_o[gd] = (unsigned short)f2bf(val - bf2f(vh));
                }
            }
        }
    }
}

// ---- out[n] = tanh(mean_c (hi+lo)) ----
__global__ void k_out(const unsigned short* __restrict__ hhi,
                      const unsigned short* __restrict__ hlo, float* __restrict__ out) {
    int wid = (blockIdx.x * blockDim.x + threadIdx.x) >> 6;
    int lane = threadIdx.x & 63;
    if (wid >= NN) return;
    ushort2 vh = ((const ushort2*)(hhi + (long long)wid * CC))[lane];
    ushort2 vl = ((const ushort2*)(hlo + (long long)wid * CC))[lane];
    float s = bf2f((short)vh.x) + bf2f((short)vl.x) + bf2f((short)vh.y) + bf2f((short)vl.y);
    for (int off = 32; off; off >>= 1) s += __shfl_down(s, off);
    if (lane == 0) out[wid] = tanhf_(s * (1.0f / 128.0f));
}

extern "C" void kernel_launch(void* const* d_in, const int* in_sizes, int n_in,
                              void* d_out, int out_size, void* d_ws, size_t ws_size,
                              hipStream_t stream) {
    const float* x = (const float*)d_in[0];
    const void* edges = d_in[1];
    const float* weight = (const float*)d_in[2];
    const float* w_ih = (const float*)d_in[3];
    const float* w_hh = (const float*)d_in[4];
    const float* b_ih = (const float*)d_in[5];
    const float* b_hh = (const float*)d_in[6];
    float* out = (float*)d_out;

    char* ws = (char*)d_ws;
    size_t off = 0;
    auto alloc = [&](size_t bytes) -> char* {
        char* p = ws + off;
        off += (bytes + 255) & ~(size_t)255;
        return p;
    };
    // total ws ~124 MB (proven-safe watermark from R4: 162.8 MB)
    int* counts = (int*)alloc((size_t)NN * 4);
    int* rowptr = (int*)alloc((size_t)(NN + 1) * 4);
    int* csr_src = (int*)alloc((size_t)NE * 4);
    float* inv_den = (float*)alloc((size_t)NN * 4);
    int* bsum = (int*)alloc((size_t)SCAN_NB * 4);
    int* boff = (int*)alloc((size_t)SCAN_NB * 4);
    int* coarse_cursor = (int*)alloc((size_t)SCAN_NB * 4);
    uint2* tmp = (uint2*)alloc((size_t)NE * 8);
    short* B1hi = (short*)alloc((size_t)3 * 65536 * 2);
    short* B1lo = (short*)alloc((size_t)3 * 65536 * 2);
    short* B2hi = (short*)alloc((size_t)3 * 32768 * 2);
    short* B2lo = (short*)alloc((size_t)3 * 32768 * 2);
    float* bvec = (float*)alloc(512 * 4);
    unsigned short* hhi0 = (unsigned short*)alloc((size_t)NN * CC * 2);
    unsigned short* hlo0 = (unsigned short*)alloc((size_t)NN * CC * 2);
    unsigned short* hhi1 = (unsigned short*)alloc((size_t)NN * CC * 2);
    unsigned short* hlo1 = (unsigned short*)alloc((size_t)NN * CC * 2);

    hipMemsetAsync(counts, 0, (size_t)NN * 4, stream);

    k_count<<<(NE + 255) / 256, 256, 0, stream>>>(edges, counts);
    k_scan1<<<SCAN_NB, SCAN_B, 0, stream>>>(counts, bsum);
    k_scan2<<<1, 512, 0, stream>>>(bsum, boff, coarse_cursor);
    k_scan3<<<SCAN_NB, SCAN_B, 0, stream>>>(counts, boff, rowptr, inv_den);
    k_part<<<(NE + 8191) / 8192, 1024, 0, stream>>>(edges, coarse_cursor, tmp);
    k_fine<<<SCAN_NB, 256, 0, stream>>>(tmp, rowptr, csr_src);
    int prep_threads = 2 * 3 * C3 * CC + 512;
    k_prep<<<(prep_threads + 255) / 256, 256, 0, stream>>>(weight, w_ih, w_hh, b_ih, b_hh,
                                                           B1hi, B1lo, B2hi, B2lo, bvec);
    k_cvt<<<(NN * CC) / 2048, 256, 0, stream>>>(x, hhi0, hlo0);

    const int blocks = (NN + 63) / 64;  // 1563
    unsigned short* hi_in = hhi0;  unsigned short* lo_in = hlo0;
    unsigned short* hi_out = hhi1; unsigned short* lo_out = hlo1;
    for (int i = 0; i < 3; i++) {
        k_fused<<<blocks, 512, 0, stream>>>(hi_in, lo_in, hi_out, lo_out,
                                            rowptr, csr_src, inv_den,
                                            B1hi + (size_t)i * 65536, B1lo + (size_t)i * 65536,
                                            B2hi + (size_t)i * 32768, B2lo + (size_t)i * 32768,
                                            bvec);
        unsigned short* th = hi_in; hi_in = hi_out; hi_out = th;
        unsigned short* tl = lo_in; lo_in = lo_out; lo_out = tl;
    }
    k_out<<<25000, 256, 0, stream>>>(hi_in, lo_in, out);
}

// Round 12
// 639.023 us; speedup vs baseline: 1.9313x; 1.1670x over previous
//
#include <hip/hip_runtime.h>
#include <math.h>

#define NN 100000
#define NE 1600000
#define CC 128
#define C3 384
#define SCAN_B 256
#define SCAN_NB ((NN + SCAN_B - 1) / SCAN_B)  // 391 (also = coarse bucket count)

typedef __attribute__((ext_vector_type(4))) float f4;
typedef __attribute__((ext_vector_type(8))) short s8;

__device__ __forceinline__ float sigmoidf_(float x) { return 1.0f / (1.0f + __expf(-x)); }
__device__ __forceinline__ float tanhf_(float x) { return 2.0f / (1.0f + __expf(-2.0f * x)) - 1.0f; }

__device__ __forceinline__ short f2bf(float x) {
    unsigned u = __float_as_uint(x);
    unsigned r = (u + 0x7fffu + ((u >> 16) & 1u)) >> 16;
    return (short)r;
}
__device__ __forceinline__ float bf2f(short s) {
    return __uint_as_float(((unsigned)(unsigned short)s) << 16);
}

// ---- edge dtype: int64 => all odd int32 words zero. Computed per-block (L1-cached). ----
__device__ __forceinline__ int detect_flag(const int* e32) {
    int allz = 1;
#pragma unroll
    for (int i = 0; i < 32; i++)
        if (e32[2 * i + 1] != 0) allz = 0;
    return allz;
}

__device__ __forceinline__ int edge_val(const void* edges, int f, long long idx) {
    return f ? (int)((const long long*)edges)[idx] : ((const int*)edges)[idx];
}

__global__ void k_count(const void* __restrict__ edges, int* __restrict__ counts) {
    __shared__ int sf;
    if (threadIdx.x == 0) sf = detect_flag((const int*)edges);
    __syncthreads();
    int f = sf;
    int e = blockIdx.x * blockDim.x + threadIdx.x;
    if (e < NE) {
        int d = edge_val(edges, f, (long long)NE + e);
        atomicAdd(&counts[d], 1);
    }
}

// ---- multi-block scan ----
__global__ void k_scan1(const int* __restrict__ counts, int* __restrict__ bsum) {
    __shared__ int red[4];
    int t = threadIdx.x;
    int i = blockIdx.x * SCAN_B + t;
    int v = (i < NN) ? counts[i] : 0;
#pragma unroll
    for (int off = 32; off; off >>= 1) v += __shfl_down(v, off);
    if ((t & 63) == 0) red[t >> 6] = v;
    __syncthreads();
    if (t == 0) bsum[blockIdx.x] = red[0] + red[1] + red[2] + red[3];
}

__global__ void k_scan2(const int* __restrict__ bsum, int* __restrict__ boff,
                        int* __restrict__ coarse_cursor) {
    __shared__ int lds[512];
    int t = threadIdx.x;
    int v = (t < SCAN_NB) ? bsum[t] : 0;
    lds[t] = v;
    __syncthreads();
    for (int off = 1; off < 512; off <<= 1) {
        int u = (t >= off) ? lds[t - off] : 0;
        __syncthreads();
        lds[t] += u;
        __syncthreads();
    }
    if (t < SCAN_NB) {
        int ex = lds[t] - v;
        boff[t] = ex;
        coarse_cursor[t] = ex;
    }
}

__global__ void k_scan3(const int* __restrict__ counts, const int* __restrict__ boff,
                        int* __restrict__ rowptr, float* __restrict__ inv_denom) {
    __shared__ int lds[SCAN_B];
    int t = threadIdx.x;
    int i = blockIdx.x * SCAN_B + t;
    int v = (i < NN) ? counts[i] : 0;
    lds[t] = v;
    __syncthreads();
    for (int off = 1; off < SCAN_B; off <<= 1) {
        int u = (t >= off) ? lds[t - off] : 0;
        __syncthreads();
        lds[t] += u;
        __syncthreads();
    }
    if (i < NN) {
        rowptr[i] = boff[blockIdx.x] + lds[t] - v;
        inv_denom[i] = 1.0f / (float)((v > 1) ? v : 1);
    }
    if (i == 0) rowptr[NN] = NE;
}

// ---- CSR build phase 1: partition into coarse-bucket-grouped (src,dst) pairs ----
__global__ __launch_bounds__(1024) void k_part(const void* __restrict__ edges,
                                               int* __restrict__ coarse_cursor,
                                               uint2* __restrict__ tmp) {
    __shared__ int hist[SCAN_NB];
    __shared__ int base[SCAN_NB];
    __shared__ int sf;
    int t = threadIdx.x;
    if (t == 0) sf = detect_flag((const int*)edges);
    long long e0 = (long long)blockIdx.x * 8192;

    for (int c = t; c < SCAN_NB; c += 1024) hist[c] = 0;
    __syncthreads();
    int f = sf;

    int src[8], dst[8];
#pragma unroll
    for (int i = 0; i < 8; i++) {
        long long e = e0 + i * 1024 + t;
        if (e < NE) {
            src[i] = edge_val(edges, f, e);
            dst[i] = edge_val(edges, f, NE + e);
            atomicAdd(&hist[dst[i] >> 8], 1);
        } else {
            dst[i] = -1;
        }
    }
    __syncthreads();
    for (int c = t; c < SCAN_NB; c += 1024) {
        int h = hist[c];
        base[c] = (h > 0) ? atomicAdd(&coarse_cursor[c], h) : 0;
        hist[c] = 0;
    }
    __syncthreads();
#pragma unroll
    for (int i = 0; i < 8; i++) {
        if (dst[i] >= 0) {
            int c = dst[i] >> 8;
            int off = atomicAdd(&hist[c], 1);
            tmp[base[c] + off] = make_uint2((unsigned)src[i], (unsigned)dst[i]);
        }
    }
}

// ---- CSR build phase 2 ----
__global__ void k_fine(const uint2* __restrict__ tmp, const int* __restrict__ rowptr,
                       int* __restrict__ csr_src) {
    __shared__ int cur[256];
    int c = blockIdx.x;
    int t = threadIdx.x;
    int d = c * 256 + t;
    cur[t] = (d <= NN) ? rowptr[d < NN ? d : NN] : NE;
    __syncthreads();
    int start = rowptr[c * 256];
    int endd = (c * 256 + 256 <= NN) ? rowptr[c * 256 + 256] : NE;
    for (int p = start + t; p < endd; p += 256) {
        uint2 pr = tmp[p];
        int slot = atomicAdd(&cur[pr.y & 255], 1);
        csr_src[slot] = (int)pr.x;
    }
}

// ---- weight prep: hi-only B matrices (B bf16-quantized; ah*bl term dropped per R12) ----
__global__ void k_prep(const float* __restrict__ weight, const float* __restrict__ w_ih,
                       const float* __restrict__ w_hh, const float* __restrict__ b_ih,
                       const float* __restrict__ b_hh,
                       short* __restrict__ B1hi, short* __restrict__ B2hi,
                       float* __restrict__ bvec) {
    const int P1 = 3 * C3 * CC;
    int gid = blockIdx.x * blockDim.x + threadIdx.x;
    if (gid < P1) {
        int i = gid / (C3 * CC);
        int rem = gid % (C3 * CC);
        int j = rem / CC;
        int k = rem % CC;
        const float* Wr = weight + i * CC * CC + k * CC;
        const float* ir = w_ih + j * CC;
        float v = 0.f;
#pragma unroll 4
        for (int c = 0; c < CC; c++) v += Wr[c] * ir[c];
        short hi = f2bf(v);
        if (j < 256) B1hi[i * 65536 + j * 256 + k] = hi;
        else B2hi[i * 32768 + (j - 256) * 128 + k] = hi;
    } else if (gid < 2 * P1) {
        int g = gid - P1;
        int i = g / (C3 * CC);
        int rem = g % (C3 * CC);
        int j = rem / CC;
        int k = rem % CC;
        short hi = f2bf(w_hh[j * CC + k]);
        if (j < 256) B1hi[i * 65536 + j * 256 + 128 + k] = hi;
        else B2hi[i * 32768 + (j - 256 + 128) * 128 + k] = hi;
    } else if (gid < 2 * P1 + 512) {
        int j = gid - 2 * P1;
        float v;
        if (j < 256) v = b_ih[j] + b_hh[j];
        else if (j < 384) v = b_ih[j];
        else v = b_hh[j - 128];
        bvec[j] = v;
    }
}

// ---- x -> split-bf16 dense hhi/hlo ----
__global__ void k_cvt(const float* __restrict__ x, unsigned short* __restrict__ hhi,
                      unsigned short* __restrict__ hlo) {
    long long g = ((long long)blockIdx.x * 256 + threadIdx.x) * 8;
    float4 v0 = *(const float4*)(x + g);
    float4 v1 = *(const float4*)(x + g + 4);
    float f[8] = {v0.x, v0.y, v0.z, v0.w, v1.x, v1.y, v1.z, v1.w};
    s8 oh, ol;
#pragma unroll
    for (int q = 0; q < 8; q++) {
        short hi = f2bf(f[q]);
        oh[q] = hi;
        ol[q] = f2bf(f[q] - bf2f(hi));
    }
    *(s8*)(hhi + g) = oh;
    *(s8*)(hlo + g) = ol;
}

// ---- FUSED layer: gather+mean -> split-A x bf16-B MFMA GEMM -> GRU -> h_out / out ----
// 64 nodes/block, 512 threads = 8 waves. A split (hi/lo) kept for precision; B bf16.
// Gather: quarter-wave (16 lanes x 16 B), 4-edge ILP. Last layer (out != null):
// LDS-reduce mean over features, write tanh directly; h arrays not written.
__global__ __launch_bounds__(512, 4) void k_fused(
    const unsigned short* __restrict__ hhi_i, const unsigned short* __restrict__ hlo_i,
    unsigned short* __restrict__ hhi_o, unsigned short* __restrict__ hlo_o,
    const int* __restrict__ rowptr, const int* __restrict__ csr_src,
    const float* __restrict__ inv_denom,
    const short* __restrict__ B1hi, const short* __restrict__ B2hi,
    const float* __restrict__ bvec, float* __restrict__ out) {
    __shared__ short Ahi[16384];
    __shared__ short Alo[16384];
    __shared__ float osum[64];
    int t = threadIdx.x;
    long long nb = (long long)blockIdx.x * 64;
    int wv = t >> 6;
    int L = t & 63;

    if (out && t < 64) osum[t] = 0.f;

    // stage h half (cols 128..255): branch-free s8 copies
#pragma unroll
    for (int i = 0; i < 2; i++) {
        int ci = t + 512 * i;
        int rr = ci >> 4;
        int c = ci & 15;
        int c4 = 16 + c;
        long long row = nb + rr;
        if (row >= NN) row = NN - 1;
        int off = (c4 >> 2) * 2048 + (rr >> 4) * 512 + (rr & 15) * 32 + (c4 & 3) * 8;
        long long gsrc = row * CC + c * 8;
        *(s8*)&Ahi[off] = *(const s8*)(hhi_i + gsrc);
        *(s8*)&Alo[off] = *(const s8*)(hlo_i + gsrc);
    }

    // gather + mean into A cols 0..127: quarter-wave per node, 4-edge ILP
    {
        int q = L >> 4;
        int l16 = L & 15;
#pragma unroll
        for (int pass = 0; pass < 2; pass++) {
            int rr = wv * 8 + pass * 4 + q;
            long long rowc = nb + rr;
            if (rowc >= NN) rowc = NN - 1;
            int lo = rowptr[rowc], hi = rowptr[rowc + 1];
            float acc0[8] = {0, 0, 0, 0, 0, 0, 0, 0};
            float acc1[8] = {0, 0, 0, 0, 0, 0, 0, 0};
            int e = lo;
            for (; e + 3 < hi; e += 4) {
                int s0 = csr_src[e];
                int s1 = csr_src[e + 1];
                int s2 = csr_src[e + 2];
                int s3 = csr_src[e + 3];
                s8 v0 = ((const s8*)(hhi_i + (long long)s0 * CC))[l16];
                s8 v1 = ((const s8*)(hhi_i + (long long)s1 * CC))[l16];
                s8 v2 = ((const s8*)(hhi_i + (long long)s2 * CC))[l16];
                s8 v3 = ((const s8*)(hhi_i + (long long)s3 * CC))[l16];
#pragma unroll
                for (int k = 0; k < 8; k++) {
                    acc0[k] += bf2f(v0[k]) + bf2f(v2[k]);
                    acc1[k] += bf2f(v1[k]) + bf2f(v3[k]);
                }
            }
            for (; e + 1 < hi; e += 2) {
                int s0 = csr_src[e];
                int s1 = csr_src[e + 1];
                s8 v0 = ((const s8*)(hhi_i + (long long)s0 * CC))[l16];
                s8 v1 = ((const s8*)(hhi_i + (long long)s1 * CC))[l16];
#pragma unroll
                for (int k = 0; k < 8; k++) {
                    acc0[k] += bf2f(v0[k]);
                    acc1[k] += bf2f(v1[k]);
                }
            }
            if (e < hi) {
                int s0 = csr_src[e];
                s8 v0 = ((const s8*)(hhi_i + (long long)s0 * CC))[l16];
#pragma unroll
                for (int k = 0; k < 8; k++) acc0[k] += bf2f(v0[k]);
            }
            float inv = inv_denom[rowc];
            s8 vh, vl;
#pragma unroll
            for (int k = 0; k < 8; k++) {
                float f = (acc0[k] + acc1[k]) * inv;
                short hi16 = f2bf(f);
                vh[k] = hi16;
                vl[k] = f2bf(f - bf2f(hi16));
            }
            int off = (l16 >> 2) * 2048 + (rr >> 4) * 512 + (rr & 15) * 32 + (l16 & 3) * 8;
            *(s8*)&Ahi[off] = vh;
            *(s8*)&Alo[off] = vl;
        }
    }
    __syncthreads();

    int lm = L & 15;
    int lq = L >> 4;
    int j = wv * 16 + lm;

    f4 aR[4], aZ[4], aN[4], aH[4];
    {
        float bR = bvec[j], bZ = bvec[128 + j], bN = bvec[256 + j], bH = bvec[384 + j];
#pragma unroll
        for (int ch = 0; ch < 4; ch++) {
            aR[ch] = (f4){bR, bR, bR, bR};
            aZ[ch] = (f4){bZ, bZ, bZ, bZ};
            aN[ch] = (f4){bN, bN, bN, bN};
            aH[ch] = (f4){bH, bH, bH, bH};
        }
    }

#pragma unroll
    for (int ks = 0; ks < 8; ks++) {
        int o1 = ks * 32 + lq * 8;
        s8 bRh = *(const s8*)(B1hi + j * 256 + o1);
        s8 bZh = *(const s8*)(B1hi + (128 + j) * 256 + o1);
        int rowG = (ks < 4) ? j : (128 + j);
        int o2 = (ks & 3) * 32 + lq * 8;
        s8 bGh = *(const s8*)(B2hi + rowG * 128 + o2);
#pragma unroll
        for (int ch = 0; ch < 4; ch++) {
            int aoff = ks * 2048 + ch * 512 + lm * 32 + lq * 8;
            s8 ah = *(const s8*)&Ahi[aoff];
            s8 al = *(const s8*)&Alo[aoff];
            aR[ch] = __builtin_amdgcn_mfma_f32_16x16x32_bf16(ah, bRh, aR[ch], 0, 0, 0);
            aR[ch] = __builtin_amdgcn_mfma_f32_16x16x32_bf16(al, bRh, aR[ch], 0, 0, 0);
            aZ[ch] = __builtin_amdgcn_mfma_f32_16x16x32_bf16(ah, bZh, aZ[ch], 0, 0, 0);
            aZ[ch] = __builtin_amdgcn_mfma_f32_16x16x32_bf16(al, bZh, aZ[ch], 0, 0, 0);
            if (ks < 4) {
                aN[ch] = __builtin_amdgcn_mfma_f32_16x16x32_bf16(ah, bGh, aN[ch], 0, 0, 0);
                aN[ch] = __builtin_amdgcn_mfma_f32_16x16x32_bf16(al, bGh, aN[ch], 0, 0, 0);
            } else {
                aH[ch] = __builtin_amdgcn_mfma_f32_16x16x32_bf16(ah, bGh, aH[ch], 0, 0, 0);
                aH[ch] = __builtin_amdgcn_mfma_f32_16x16x32_bf16(al, bGh, aH[ch], 0, 0, 0);
            }
        }
    }

    // register-only GRU epilogue
    {
        int c4 = 16 + (j >> 3);
        int obase = (c4 >> 2) * 2048 + (c4 & 3) * 8 + (j & 7);
#pragma unroll
        for (int ch = 0; ch < 4; ch++) {
#pragma unroll
            for (int r = 0; r < 4; r++) {
                int node = ch * 16 + lq * 4 + r;
                int off = obase + ch * 512 + (node & 15) * 32;
                float hp = bf2f(Ahi[off]) + bf2f(Alo[off]);
                float rg = sigmoidf_(aR[ch][r]);
                float zg = sigmoidf_(aZ[ch][r]);
                float nv = tanhf_(aN[ch][r] + rg * aH[ch][r]);
                float val = (1.f - zg) * nv + zg * hp;
                long long gnode = nb + node;
                if (out) {
                    atomicAdd(&osum[node], val);
                } else if (gnode < NN) {
                    long long gd = gnode * CC + j;
                    short vh = f2bf(val);
                    hhi_o[gd] = (unsigned short)vh;
                    hlo_o[gd] = (unsigned short)f2bf(val - bf2f(vh));
                }
            }
        }
    }
    if (out) {
        __syncthreads();
        if (t < 64 && nb + t < NN)
            out[nb + t] = tanhf_(osum[t] * (1.0f / 128.0f));
    }
}

extern "C" void kernel_launch(void* const* d_in, const int* in_sizes, int n_in,
                              void* d_out, int out_size, void* d_ws, size_t ws_size,
                              hipStream_t stream) {
    const float* x = (const float*)d_in[0];
    const void* edges = d_in[1];
    const float* weight = (const float*)d_in[2];
    const float* w_ih = (const float*)d_in[3];
    const float* w_hh = (const float*)d_in[4];
    const float* b_ih = (const float*)d_in[5];
    const float* b_hh = (const float*)d_in[6];
    float* out = (float*)d_out;

    char* ws = (char*)d_ws;
    size_t off = 0;
    auto alloc = [&](size_t bytes) -> char* {
        char* p = ws + off;
        off += (bytes + 255) & ~(size_t)255;
        return p;
    };
    // total ws ~122 MB (proven-safe watermark from R4: 162.8 MB)
    int* counts = (int*)alloc((size_t)NN * 4);
    int* rowptr = (int*)alloc((size_t)(NN + 1) * 4);
    int* csr_src = (int*)alloc((size_t)NE * 4);
    float* inv_den = (float*)alloc((size_t)NN * 4);
    int* bsum = (int*)alloc((size_t)SCAN_NB * 4);
    int* boff = (int*)alloc((size_t)SCAN_NB * 4);
    int* coarse_cursor = (int*)alloc((size_t)SCAN_NB * 4);
    uint2* tmp = (uint2*)alloc((size_t)NE * 8);
    short* B1hi = (short*)alloc((size_t)3 * 65536 * 2);
    short* B2hi = (short*)alloc((size_t)3 * 32768 * 2);
    float* bvec = (float*)alloc(512 * 4);
    unsigned short* hhi0 = (unsigned short*)alloc((size_t)NN * CC * 2);
    unsigned short* hlo0 = (unsigned short*)alloc((size_t)NN * CC * 2);
    unsigned short* hhi1 = (unsigned short*)alloc((size_t)NN * CC * 2);
    unsigned short* hlo1 = (unsigned short*)alloc((size_t)NN * CC * 2);

    hipMemsetAsync(counts, 0, (size_t)NN * 4, stream);

    k_count<<<(NE + 255) / 256, 256, 0, stream>>>(edges, counts);
    k_scan1<<<SCAN_NB, SCAN_B, 0, stream>>>(counts, bsum);
    k_scan2<<<1, 512, 0, stream>>>(bsum, boff, coarse_cursor);
    k_scan3<<<SCAN_NB, SCAN_B, 0, stream>>>(counts, boff, rowptr, inv_den);
    k_part<<<(NE + 8191) / 8192, 1024, 0, stream>>>(edges, coarse_cursor, tmp);
    k_fine<<<SCAN_NB, 256, 0, stream>>>(tmp, rowptr, csr_src);
    int prep_threads = 2 * 3 * C3 * CC + 512;
    k_prep<<<(prep_threads + 255) / 256, 256, 0, stream>>>(weight, w_ih, w_hh, b_ih, b_hh,
                                                           B1hi, B2hi, bvec);
    k_cvt<<<(NN * CC) / 2048, 256, 0, stream>>>(x, hhi0, hlo0);

    const int blocks = (NN + 63) / 64;  // 1563
    unsigned short* hi_in = hhi0;  unsigned short* lo_in = hlo0;
    unsigned short* hi_out = hhi1; unsigned short* lo_out = hlo1;
    for (int i = 0; i < 3; i++) {
        float* outp = (i == 2) ? out : nullptr;
        k_fused<<<blocks, 512, 0, stream>>>(hi_in, lo_in, hi_out, lo_out,
                                            rowptr, csr_src, inv_den,
                                            B1hi + (size_t)i * 65536,
                                            B2hi + (size_t)i * 32768,
                                            bvec, outp);
        unsigned short* th = hi_in; hi_in = hi_out; hi_out = th;
        unsigned short* tl = lo_in; lo_in = lo_out; lo_out = tl;
    }
}